// Round 9
// baseline (464.717 us; speedup 1.0000x reference)
//
#include <hip/hip_runtime.h>
#include <hip/hip_bf16.h>
#include <math.h>

#define BB 4
#define TT 2048
#define CC 512
#define QQ 300
#define NWW 32
#define MDD 256
#define WSS 16
#define NCC 4
#define SS 16
#define LL (TT - WSS + 1)   // 2033
#define NSUB 8
#define PUL (TT - 3)        // 2045 pu rows per batch

typedef __attribute__((ext_vector_type(8))) short short8;
typedef __attribute__((ext_vector_type(4))) short short4v;
typedef __attribute__((ext_vector_type(4))) float f32x4;

// ---------------------------------------------------------------------------
// PE add — expression kept VERBATIM identical to the frozen path.
// ---------------------------------------------------------------------------
__device__ __forceinline__ void pe_add4(f32x4& v, int t, int gk0)
{
    #pragma unroll
    for (int j = 0; j < 4; j++) {
        int gk = gk0 + j;
        float di = expf((float)(gk & ~1) * (-9.210340371976184f / (float)CC));
        float ang = (float)t * di;
        v[j] += (gk & 1) ? cosf(ang) : sinf(ang);
    }
}

// ---------------------------------------------------------------------------
// fp32 GEMM for the v-path (steps 1,2). BIT-IDENTICAL VALUES: per output a
// single fp32 accumulator, k strictly ascending, one `acc += a*b` statement.
// R9: 128x128 tile, 8x8/thread (best ds_read:fma ratio, 4:64), B-cols split
// {tx*4, 64+tx*4} (2-way bank aliasing = free), dbuf LDS, ONE barrier/K-step,
// register prefetch. Grid 256 = 1 block/CU.
// ---------------------------------------------------------------------------
template<int PE>
__global__ __launch_bounds__(256, 1) void gemm_f32_fast(
    const float* __restrict__ A, const float* __restrict__ Bm,
    const float* __restrict__ bias, float* __restrict__ Cm,
    int M, int N, int K, int do_relu)
{
    __shared__ float As[2][32][132];   // k-major, padded
    __shared__ float Bs[2][32][132];
    const int bm = blockIdx.x * 128;
    const int bn = blockIdx.y * 128;
    const int tid = threadIdx.x;
    const int tx = tid & 15;        // n: quads at tx*4 and 64+tx*4
    const int ty = tid >> 4;        // m: rows ty*8 .. ty*8+7

    float acc[8][8] = {};
    f32x4 pa[4], pb[4];
    int am[4], akq[4], bkr[4], bnq[4];
    #pragma unroll
    for (int i = 0; i < 4; i++) {
        int idx = i * 256 + tid;
        am[i]  = idx >> 3;  akq[i] = (idx & 7) * 4;    // A: 128 rows x 32 k
        bkr[i] = idx >> 5;  bnq[i] = (idx & 31) * 4;   // B: 32 k x 128 n
    }

    const int nk0 = K / 32;
    #pragma unroll
    for (int i = 0; i < 4; i++) {
        pa[i] = *(const f32x4*)(A + (size_t)(bm + am[i]) * K + akq[i]);
        if (PE) pe_add4(pa[i], (bm + am[i]) & (TT - 1), akq[i]);
        pb[i] = *(const f32x4*)(Bm + (size_t)bkr[i] * N + bn + bnq[i]);
    }

    int buf = 0;
    for (int k0i = 0; ; k0i++) {
        #pragma unroll
        for (int i = 0; i < 4; i++) {
            #pragma unroll
            for (int j = 0; j < 4; j++) As[buf][akq[i] + j][am[i]] = pa[i][j];
            *(f32x4*)&Bs[buf][bkr[i]][bnq[i]] = pb[i];
        }
        __syncthreads();            // single barrier per K-step (dbuf)
        if (k0i + 1 < nk0) {
            int k0 = (k0i + 1) * 32;
            #pragma unroll
            for (int i = 0; i < 4; i++) {
                pa[i] = *(const f32x4*)(A + (size_t)(bm + am[i]) * K + k0 + akq[i]);
                if (PE) pe_add4(pa[i], (bm + am[i]) & (TT - 1), k0 + akq[i]);
                pb[i] = *(const f32x4*)(Bm + (size_t)(k0 + bkr[i]) * N + bn + bnq[i]);
            }
        }
        #pragma unroll 4
        for (int kk = 0; kk < 32; kk++) {
            f32x4 a0 = *(const f32x4*)&As[buf][kk][ty * 8];
            f32x4 a1 = *(const f32x4*)&As[buf][kk][ty * 8 + 4];
            f32x4 b0 = *(const f32x4*)&Bs[buf][kk][tx * 4];
            f32x4 b1 = *(const f32x4*)&Bs[buf][kk][64 + tx * 4];
            #pragma unroll
            for (int i2 = 0; i2 < 4; i2++)
                #pragma unroll
                for (int j2 = 0; j2 < 4; j2++) {
                    acc[i2][j2]         += a0[i2] * b0[j2];
                    acc[i2][j2 + 4]     += a0[i2] * b1[j2];
                    acc[i2 + 4][j2]     += a1[i2] * b0[j2];
                    acc[i2 + 4][j2 + 4] += a1[i2] * b1[j2];
                }
        }
        buf ^= 1;
        if (k0i + 1 == nk0) break;
    }

    #pragma unroll
    for (int i = 0; i < 8; i++) {
        int gm = bm + ty * 8 + i;
        f32x4 o0, o1;
        #pragma unroll
        for (int j = 0; j < 4; j++) {
            float v0 = acc[i][j]     + bias[bn + tx * 4 + j];
            float v1 = acc[i][j + 4] + bias[bn + 64 + tx * 4 + j];
            if (do_relu) { v0 = fmaxf(v0, 0.f); v1 = fmaxf(v1, 0.f); }
            o0[j] = v0; o1[j] = v1;
        }
        *(f32x4*)(Cm + (size_t)gm * N + bn + tx * 4)      = o0;
        *(f32x4*)(Cm + (size_t)gm * N + bn + 64 + tx * 4) = o1;
    }
}

// ---------------------------------------------------------------------------
// Fused query path: qpe (PE verbatim) + both 2-layer MLPs, one block per row.
// Every output keeps the PROVEN bit-identical strict ascending-k fmaf chain
// with group-10 prefetch (== sgemm_exact). enc1 feeds the argmax — exact.
// ---------------------------------------------------------------------------
__global__ __launch_bounds__(256) void query_fused(
    const float* __restrict__ qf,
    const float* __restrict__ s1W1, const float* __restrict__ s1b1,
    const float* __restrict__ s1W2, const float* __restrict__ s1b2,
    const float* __restrict__ s2W1, const float* __restrict__ s2b1,
    const float* __restrict__ s2W2, const float* __restrict__ s2b2,
    float* __restrict__ enc1, float* __restrict__ enc2)
{
    __shared__ float qrow[QQ];
    __shared__ float h1row[QQ];
    __shared__ float h2row[QQ];
    const int m = blockIdx.x;          // 0 .. B*NW-1
    const int w = m % NWW;
    const int tid = threadIdx.x;

    for (int qi = tid; qi < QQ; qi += 256) {
        float di = expf((float)(qi & ~1) * (-9.210340371976184f / (float)QQ));
        float ang = (float)w * di;
        qrow[qi] = qf[(size_t)m * QQ + qi] + ((qi & 1) ? cosf(ang) : sinf(ang));
    }
    __syncthreads();

    // layer 1 (both heads): strict chain per output
    for (int n = tid; n < QQ; n += 256) {
        const float* b1p = s1W1 + n;
        const float* b2p = s2W1 + n;
        float a1 = 0.f, a2 = 0.f;
        int k = 0;
        for (; k + 10 <= QQ; k += 10) {
            float av[10], bv1[10], bv2[10];
            #pragma unroll
            for (int u = 0; u < 10; u++) av[u] = qrow[k + u];
            #pragma unroll
            for (int u = 0; u < 10; u++) bv1[u] = b1p[(size_t)(k + u) * QQ];
            #pragma unroll
            for (int u = 0; u < 10; u++) bv2[u] = b2p[(size_t)(k + u) * QQ];
            #pragma unroll
            for (int u = 0; u < 10; u++) a1 = fmaf(av[u], bv1[u], a1);
            #pragma unroll
            for (int u = 0; u < 10; u++) a2 = fmaf(av[u], bv2[u], a2);
        }
        for (; k < QQ; k++) {
            a1 = fmaf(qrow[k], b1p[(size_t)k * QQ], a1);
            a2 = fmaf(qrow[k], b2p[(size_t)k * QQ], a2);
        }
        h1row[n] = fmaxf(a1 + s1b1[n], 0.f);
        h2row[n] = fmaxf(a2 + s2b1[n], 0.f);
    }
    __syncthreads();

    // layer 2 (both heads): strict chain per output
    for (int n = tid; n < CC; n += 256) {
        const float* b1p = s1W2 + n;
        const float* b2p = s2W2 + n;
        float a1 = 0.f, a2 = 0.f;
        int k = 0;
        for (; k + 10 <= QQ; k += 10) {
            float av1[10], av2[10], bv1[10], bv2[10];
            #pragma unroll
            for (int u = 0; u < 10; u++) av1[u] = h1row[k + u];
            #pragma unroll
            for (int u = 0; u < 10; u++) av2[u] = h2row[k + u];
            #pragma unroll
            for (int u = 0; u < 10; u++) bv1[u] = b1p[(size_t)(k + u) * CC];
            #pragma unroll
            for (int u = 0; u < 10; u++) bv2[u] = b2p[(size_t)(k + u) * CC];
            #pragma unroll
            for (int u = 0; u < 10; u++) a1 = fmaf(av1[u], bv1[u], a1);
            #pragma unroll
            for (int u = 0; u < 10; u++) a2 = fmaf(av2[u], bv2[u], a2);
        }
        for (; k < QQ; k++) {
            a1 = fmaf(h1row[k], b1p[(size_t)k * CC], a1);
            a2 = fmaf(h2row[k], b2p[(size_t)k * CC], a2);
        }
        enc1[(size_t)m * CC + n] = a1 + s1b2[n];
        enc2[(size_t)m * CC + n] = a2 + s2b2[n];
    }
}

// ---------------------------------------------------------------------------
// bf16 MFMA GEMM (continuous-output path only): unchanged from R3.
// ---------------------------------------------------------------------------
__global__ __launch_bounds__(256) void gemm_bf16_kernel(
    const short* __restrict__ A,   // [M,K] bf16 bits
    const short* __restrict__ Bt,  // [N,K] bf16 bits
    const float* __restrict__ bias, float* __restrict__ C,
    int M, int N, int K, int do_relu)
{
    __shared__ short As[128][40];
    __shared__ short Bs[128][40];
    const int bm = blockIdx.x * 128;
    const int bn = blockIdx.y * 128;
    const int tid = threadIdx.x;
    const int wave = tid >> 6, lane = tid & 63;
    const int wm = (wave & 1) * 64, wn = (wave >> 1) * 64;
    const int l15 = lane & 15, lk = (lane >> 4) * 8;
    const int srow = tid >> 2;
    const int scol = (tid & 3) * 8;

    f32x4 acc[4][4] = {};

    for (int k0 = 0; k0 < K; k0 += 32) {
        #pragma unroll
        for (int p = 0; p < 2; p++) {
            int row = p * 64 + srow;
            short8 av = {};
            int gm = bm + row;
            if (gm < M) av = *(const short8*)(A + (size_t)gm * K + k0 + scol);
            *(short8*)&As[row][scol] = av;
            short8 bv = {};
            int gn = bn + row;
            if (gn < N) bv = *(const short8*)(Bt + (size_t)gn * K + k0 + scol);
            *(short8*)&Bs[row][scol] = bv;
        }
        __syncthreads();

        short8 af[4], bf[4];
        #pragma unroll
        for (int mi = 0; mi < 4; mi++)
            af[mi] = *(const short8*)&As[wm + mi * 16 + l15][lk];
        #pragma unroll
        for (int ni = 0; ni < 4; ni++)
            bf[ni] = *(const short8*)&Bs[wn + ni * 16 + l15][lk];
        #pragma unroll
        for (int mi = 0; mi < 4; mi++)
            #pragma unroll
            for (int ni = 0; ni < 4; ni++)
                acc[mi][ni] = __builtin_amdgcn_mfma_f32_16x16x32_bf16(
                    af[mi], bf[ni], acc[mi][ni], 0, 0, 0);
        __syncthreads();
    }

    #pragma unroll
    for (int mi = 0; mi < 4; mi++) {
        int row0 = bm + wm + mi * 16 + (lane >> 4) * 4;
        #pragma unroll
        for (int ni = 0; ni < 4; ni++) {
            int col = bn + wn + ni * 16 + l15;
            float bsv = bias ? bias[col] : 0.f;
            #pragma unroll
            for (int r = 0; r < 4; r++) {
                int grow = row0 + r;
                if (grow >= M) continue;
                float val = acc[mi][ni][r] + bsv;
                if (do_relu) val = fmaxf(val, 0.f);
                C[(size_t)grow * N + col] = val;
            }
        }
    }
}

// ---------------------------------------------------------------------------
// LDS-tiled transpose+convert: dst[n][k] = bf16(src[k][n]). K,N % 32 == 0.
// ---------------------------------------------------------------------------
__global__ __launch_bounds__(256) void convT2_kernel(
    const float* __restrict__ src, __hip_bfloat16* __restrict__ dst,
    int K, int N)
{
    __shared__ float t[32][33];
    int c = threadIdx.x & 31, r4 = threadIdx.x >> 5;   // 32 x 8
    int n0 = blockIdx.x * 32, k0 = blockIdx.y * 32;
    #pragma unroll
    for (int rr = 0; rr < 32; rr += 8)
        t[rr + r4][c] = src[(size_t)(k0 + rr + r4) * N + n0 + c];
    __syncthreads();
    #pragma unroll
    for (int rr = 0; rr < 32; rr += 8)
        dst[(size_t)(n0 + rr + r4) * K + k0 + c] = __float2bfloat16(t[c][rr + r4]);
}

// ---------------------------------------------------------------------------
// sim[b,t,w] = sum_c v[b,t,c] * enc1[b,w,c]   (bit-identical chain)
// ---------------------------------------------------------------------------
__global__ __launch_bounds__(256) void sim_kernel(
    const float* __restrict__ v, const float* __restrict__ enc1,
    float* __restrict__ sim)
{
    __shared__ float vs[8][CC];
    int blk = blockIdx.x;
    int b  = blk / (TT / 8);
    int t0 = (blk % (TT / 8)) * 8;
    int tid = threadIdx.x;
    for (int i = tid; i < 8 * (CC / 4); i += 256) {
        int r = i / (CC / 4), c = i % (CC / 4);
        *(f32x4*)&vs[r][c * 4] =
            *(const f32x4*)(v + ((size_t)b * TT + t0 + r) * CC + c * 4);
    }
    __syncthreads();
    int w  = tid & 31;
    int tt = tid >> 5;
    const f32x4* e4 = (const f32x4*)(enc1 + ((size_t)b * NWW + w) * CC);
    const f32x4* v4 = (const f32x4*)vs[tt];
    float s = 0.f;
    #pragma unroll 4
    for (int kq = 0; kq < CC / 4; kq++) {
        f32x4 vv = v4[kq], ee = e4[kq];
        s = fmaf(vv[0], ee[0], s);
        s = fmaf(vv[1], ee[1], s);
        s = fmaf(vv[2], ee[2], s);
        s = fmaf(vv[3], ee[3], s);
    }
    sim[((size_t)b * TT + t0 + tt) * NWW + w] = s;
}

// ---------------------------------------------------------------------------
// pu[b,t,:] = 0.25*(((v[t]+v[t+1])+v[t+2])+v[t+3])  — expression verbatim.
// ---------------------------------------------------------------------------
__global__ __launch_bounds__(256) void pu_kernel(
    const float* __restrict__ v, float* __restrict__ pu)
{
    int idx = blockIdx.x * 256 + threadIdx.x;     // over B*PUL*(C/4)
    if (idx >= BB * PUL * (CC / 4)) return;
    int q = idx % (CC / 4);
    int t = (idx / (CC / 4)) % PUL;
    int b = idx / ((CC / 4) * PUL);
    const float* vp = v + ((size_t)b * TT + t) * CC + q * 4;
    f32x4 r0 = *(const f32x4*)vp;
    f32x4 r1 = *(const f32x4*)(vp + CC);
    f32x4 r2 = *(const f32x4*)(vp + 2 * CC);
    f32x4 r3 = *(const f32x4*)(vp + 3 * CC);
    f32x4 o;
    #pragma unroll
    for (int j = 0; j < 4; j++)
        o[j] = 0.25f * (((r0[j] + r1[j]) + r2[j]) + r3[j]);
    *(f32x4*)(pu + ((size_t)b * PUL + t) * CC + q * 4) = o;
}

// ---------------------------------------------------------------------------
// Per (b,l): bel argmax (VERBATIM frozen code) + gather + modulate via pu
// ---------------------------------------------------------------------------
__global__ __launch_bounds__(256) void mod_kernel(
    const float* __restrict__ pu, const float* __restrict__ sim,
    const float* __restrict__ enc2, __hip_bfloat16* __restrict__ modb)
{
    int blk = blockIdx.x;                  // b*L + l
    int b = blk / LL, l = blk % LL;
    int tid = threadIdx.x;
    int cch = tid >> 6;
    int lane = tid & 63;
    int t0 = l + cch * 4;

    int w = lane & 31;
    const float* sp = sim + ((size_t)b * TT + t0) * NWW + w;
    float bel = sp[0] + sp[NWW] + sp[2 * NWW] + sp[3 * NWW];
    int idx = w;
    #pragma unroll
    for (int m = 1; m < 32; m <<= 1) {
        float ov = __shfl_xor(bel, m);
        int   oi = __shfl_xor(idx, m);
        if (ov > bel || (ov == bel && oi < idx)) { bel = ov; idx = oi; }
    }

    const f32x4* e2 = (const f32x4*)(enc2 + ((size_t)b * NWW + idx) * CC);
    const f32x4* pq = (const f32x4*)(pu + ((size_t)b * PUL + t0) * CC);
    __hip_bfloat16* mp = modb + (((size_t)blk) * NCC + cch) * CC;
    #pragma unroll
    for (int q = lane; q < CC / 4; q += 64) {
        f32x4 e = e2[q], p = pq[q];
        short4v o;
        #pragma unroll
        for (int j = 0; j < 4; j++) {
            __hip_bfloat16 h = __float2bfloat16(e[j] * p[j]);
            o[j] = *(short*)&h;
        }
        *(short4v*)(mp + q * 4) = o;
    }
}

// ---------------------------------------------------------------------------
// pred head 2, wave-parallel: one wave per row, both outputs.
// ---------------------------------------------------------------------------
__global__ __launch_bounds__(256) void pred2w_kernel(
    const float* __restrict__ hpred, const float* __restrict__ pW2,
    const float* __restrict__ pb2, float* __restrict__ out)
{
    int row = blockIdx.x * 4 + (threadIdx.x >> 6);
    if (row >= BB * LL) return;
    int lane = threadIdx.x & 63;
    const float* h = hpred + (size_t)row * CC + lane * 8;
    f32x4 h0 = *(const f32x4*)h;
    f32x4 h1 = *(const f32x4*)(h + 4);
    const float* wp = pW2 + lane * 16;
    f32x4 w0 = *(const f32x4*)wp;
    f32x4 w1 = *(const f32x4*)(wp + 4);
    f32x4 w2 = *(const f32x4*)(wp + 8);
    f32x4 w3 = *(const f32x4*)(wp + 12);
    float s0 = h0[0]*w0[0] + h0[1]*w0[2] + h0[2]*w1[0] + h0[3]*w1[2]
             + h1[0]*w2[0] + h1[1]*w2[2] + h1[2]*w3[0] + h1[3]*w3[2];
    float s1 = h0[0]*w0[1] + h0[1]*w0[3] + h0[2]*w1[1] + h0[3]*w1[3]
             + h1[0]*w2[1] + h1[1]*w2[3] + h1[2]*w3[1] + h1[3]*w3[3];
    #pragma unroll
    for (int m = 32; m; m >>= 1) {
        s0 += __shfl_xor(s0, m);
        s1 += __shfl_xor(s1, m);
    }
    if (lane == 0) {
        int b = row / LL, l = row % LL;
        out[((size_t)b * 2 + 0) * LL + l] = s0 + pb2[0];
        out[((size_t)b * 2 + 1) * LL + l] = s1 + pb2[1];
    }
}

// ---------------------------------------------------------------------------
// ragged adaptive max-pool, two-stage (max is exactly associative)
// ---------------------------------------------------------------------------
__global__ __launch_bounds__(256) void pool1_kernel(
    const float* __restrict__ x, const int* __restrict__ vis_len,
    float* __restrict__ scratch)
{
    int blk = blockIdx.x;             // ((b*SS + s)*NSUB + sub)
    int sub = blk % NSUB;
    int s   = (blk / NSUB) % SS;
    int b   = blk / (NSUB * SS);
    int n = vis_len[b] * NCC;
    int st = (n * s) / SS;
    int en = (n * (s + 1) + SS - 1) / SS;
    int len = en - st;
    int j0 = st + (len * sub) / NSUB;
    int j1 = st + (len * (sub + 1)) / NSUB;
    int md = threadIdx.x;
    float m = -INFINITY;
    const float* xp = x + (size_t)b * (LL * NCC) * MDD + md;
    for (int j = j0; j < j1; j++) m = fmaxf(m, xp[(size_t)j * MDD]);
    scratch[(size_t)blk * MDD + md] = m;
}

__global__ __launch_bounds__(256) void pool2_kernel(
    const float* __restrict__ scratch, float* __restrict__ feat)
{
    int blk = blockIdx.x;  // b*SS + s
    int md = threadIdx.x;
    const float* sp = scratch + (size_t)blk * NSUB * MDD + md;
    float m = sp[0];
    #pragma unroll
    for (int i = 1; i < NSUB; i++) m = fmaxf(m, sp[(size_t)i * MDD]);
    int b = blk / SS, s = blk % SS;
    feat[(size_t)b * MDD * SS + md * SS + s] = m;
}

// ---------------------------------------------------------------------------
// start/end heads
// ---------------------------------------------------------------------------
__global__ void stend_kernel(const float* __restrict__ feat,
                             const float* __restrict__ stW, const float* __restrict__ stb,
                             const float* __restrict__ enW, const float* __restrict__ enb,
                             float* __restrict__ out)
{
    int bid = blockIdx.x;                  // 0..127
    int which = bid >> 6;
    int r = bid & 63;
    int b = r >> 4, s = r & 15;
    int lane = threadIdx.x;                // 64
    const float* W  = which ? enW : stW;
    const float* bb = which ? enb : stb;
    const float* f  = feat + (size_t)b * MDD * SS;
    float acc = 0.f;
    for (int k = lane; k < MDD * SS; k += 64) acc += f[k] * W[(size_t)k * SS + s];
    #pragma unroll
    for (int m = 32; m; m >>= 1) acc += __shfl_xor(acc, m);
    if (lane == 0)
        out[(size_t)BB * 2 * LL + which * (BB * SS) + b * SS + s] = acc + bb[s];
}

// ---------------------------------------------------------------------------
extern "C" void kernel_launch(void* const* d_in, const int* in_sizes, int n_in,
                              void* d_out, int out_size, void* d_ws, size_t ws_size,
                              hipStream_t stream)
{
    const float* vis  = (const float*)d_in[0];
    const float* qf   = (const float*)d_in[1];
    const float* vW1  = (const float*)d_in[2];  const float* vb1 = (const float*)d_in[3];
    const float* vW2  = (const float*)d_in[4];  const float* vb2 = (const float*)d_in[5];
    const float* s1W1 = (const float*)d_in[6];  const float* s1b1= (const float*)d_in[7];
    const float* s1W2 = (const float*)d_in[8];  const float* s1b2= (const float*)d_in[9];
    const float* s2W1 = (const float*)d_in[10]; const float* s2b1= (const float*)d_in[11];
    const float* s2W2 = (const float*)d_in[12]; const float* s2b2= (const float*)d_in[13];
    const float* pW1  = (const float*)d_in[14]; const float* pb1 = (const float*)d_in[15];
    const float* pW2  = (const float*)d_in[16]; const float* pb2 = (const float*)d_in[17];
    const float* mW   = (const float*)d_in[18]; const float* mb  = (const float*)d_in[19];
    const float* stW  = (const float*)d_in[20]; const float* stb = (const float*)d_in[21];
    const float* enW  = (const float*)d_in[22]; const float* enb = (const float*)d_in[23];
    const int*   vlen = (const int*)d_in[24];
    float* out = (float*)d_out;

    // workspace layout (floats; 16B-aligned blocks)
    float* ws   = (float*)d_ws;
    float* h1   = ws;                                 // B*T*C (reused: pu, then hpred)
    float* v    = h1   + (size_t)BB * TT * CC;        // B*T*C
    float* qpe  = v    + (size_t)BB * TT * CC;        // (unused, layout kept)
    float* qh   = qpe  + (size_t)BB * NWW * QQ;       // (unused)
    float* enc1 = qh   + (size_t)BB * NWW * QQ;       // B*NW*C
    float* enc2 = enc1 + (size_t)BB * NWW * CC;       // B*NW*C
    float* sim  = enc2 + (size_t)BB * NWW * CC;       // B*T*NW (reused as pool scratch)
    float* feat = sim  + (size_t)BB * TT * NWW;       // B*MD*S
    float* x    = feat + (size_t)BB * MDD * SS;       // B*L*NC*MD
    float* fend = x    + (size_t)BB * LL * NCC * MDD;
    __hip_bfloat16* modb = (__hip_bfloat16*)fend;                  // MX*C bf16
    __hip_bfloat16* pW1t = modb + (size_t)BB * LL * NCC * CC;      // 512*2048 bf16
    __hip_bfloat16* mWt  = pW1t + (size_t)CC * (NCC * CC);         // 256*512 bf16

    const int MT = BB * TT;            // 8192
    const int ML = BB * LL;            // 8132
    const int MX = BB * LL * NCC;      // 32528

    // weight convert+transpose (bf16), LDS-tiled
    convT2_kernel<<<dim3(CC / 32, (NCC * CC) / 32), 256, 0, stream>>>(pW1, pW1t, NCC * CC, CC);
    convT2_kernel<<<dim3(MDD / 32, CC / 32), 256, 0, stream>>>(mW, mWt, CC, MDD);

    // 1. h1 = relu(PE(vis) @ vW1 + vb1)   (fp32 — bit-identical values)
    gemm_f32_fast<1><<<dim3(MT / 128, CC / 128), 256, 0, stream>>>(
        vis, vW1, vb1, h1, MT, CC, CC, 1);
    // 2. v = h1 @ vW2 + vb2
    gemm_f32_fast<0><<<dim3(MT / 128, CC / 128), 256, 0, stream>>>(
        h1, vW2, vb2, v, MT, CC, CC, 0);
    // 3-7. fused query path (qpe + both MLPs), one launch
    query_fused<<<BB * NWW, 256, 0, stream>>>(
        qf, s1W1, s1b1, s1W2, s1b2, s2W1, s2b1, s2W2, s2b2, enc1, enc2);
    // 8. sim
    sim_kernel<<<BB * (TT / 8), 256, 0, stream>>>(v, enc1, sim);
    // 8b. pu into h1 (dead until step 11)
    pu_kernel<<<(BB * PUL * (CC / 4) + 255) / 256, 256, 0, stream>>>(v, h1);
    // 9. mod (argmax verbatim; modulate via pu)
    mod_kernel<<<BB * LL, 256, 0, stream>>>(h1, sim, enc2, modb);
    // 10. x = mod @ mW + mb   [MX, MD]  (bf16 MFMA)
    gemm_bf16_kernel<<<dim3((MX + 127) / 128, MDD / 128), 256, 0, stream>>>(
        (const short*)modb, (const short*)mWt, mb, x, MX, MDD, CC, 0);
    // 11. hpred = relu(mod @ pW1 + pb1)  [ML, C], K=2048 (bf16 MFMA; h1 reused)
    gemm_bf16_kernel<<<dim3((ML + 127) / 128, CC / 128), 256, 0, stream>>>(
        (const short*)modb, (const short*)pW1t, pb1, h1, ML, CC, NCC * CC, 1);
    // 12. pred head -> out (wave-parallel)
    pred2w_kernel<<<(ML + 3) / 4, 256, 0, stream>>>(h1, pW2, pb2, out);
    // 13. ragged adaptive max-pool, two-stage (sim buffer reused as scratch)
    pool1_kernel<<<BB * SS * NSUB, 256, 0, stream>>>(x, vlen, sim);
    pool2_kernel<<<BB * SS, 256, 0, stream>>>(sim, feat);
    // 14. start/end heads
    stend_kernel<<<128, 64, 0, stream>>>(feat, stW, stb, enW, enb, out);
}

// Round 10
// 411.523 us; speedup vs baseline: 1.1293x; 1.1293x over previous
//
#include <hip/hip_runtime.h>
#include <hip/hip_bf16.h>
#include <math.h>

#define BB 4
#define TT 2048
#define CC 512
#define QQ 300
#define NWW 32
#define MDD 256
#define WSS 16
#define NCC 4
#define SS 16
#define LL (TT - WSS + 1)   // 2033
#define NSUB 8
#define PUL (TT - 3)        // 2045 pu rows per batch

typedef __attribute__((ext_vector_type(8))) short short8;
typedef __attribute__((ext_vector_type(4))) short short4v;
typedef __attribute__((ext_vector_type(4))) float f32x4;

// ---------------------------------------------------------------------------
// PE add — expression kept VERBATIM identical to the frozen path.
// ---------------------------------------------------------------------------
__device__ __forceinline__ void pe_add4(f32x4& v, int t, int gk0)
{
    #pragma unroll
    for (int j = 0; j < 4; j++) {
        int gk = gk0 + j;
        float di = expf((float)(gk & ~1) * (-9.210340371976184f / (float)CC));
        float ang = (float)t * di;
        v[j] += (gk & 1) ? cosf(ang) : sinf(ang);
    }
}

// ---------------------------------------------------------------------------
// fp32 GEMM for the v-path (steps 1,2). BIT-IDENTICAL VALUES: per output a
// single fp32 accumulator, k strictly ascending, one `acc += a*b` statement.
// 128x128 tile, 8x8/thread (4 ds_read : 64 fma), dbuf LDS, one barrier/step.
// ---------------------------------------------------------------------------
template<int PE>
__global__ __launch_bounds__(256, 1) void gemm_f32_fast(
    const float* __restrict__ A, const float* __restrict__ Bm,
    const float* __restrict__ bias, float* __restrict__ Cm,
    int M, int N, int K, int do_relu)
{
    __shared__ float As[2][32][132];   // k-major, padded
    __shared__ float Bs[2][32][132];
    const int bm = blockIdx.x * 128;
    const int bn = blockIdx.y * 128;
    const int tid = threadIdx.x;
    const int tx = tid & 15;        // n: quads at tx*4 and 64+tx*4
    const int ty = tid >> 4;        // m: rows ty*8 .. ty*8+7

    float acc[8][8] = {};
    f32x4 pa[4], pb[4];
    int am[4], akq[4], bkr[4], bnq[4];
    #pragma unroll
    for (int i = 0; i < 4; i++) {
        int idx = i * 256 + tid;
        am[i]  = idx >> 3;  akq[i] = (idx & 7) * 4;    // A: 128 rows x 32 k
        bkr[i] = idx >> 5;  bnq[i] = (idx & 31) * 4;   // B: 32 k x 128 n
    }

    const int nk0 = K / 32;
    #pragma unroll
    for (int i = 0; i < 4; i++) {
        pa[i] = *(const f32x4*)(A + (size_t)(bm + am[i]) * K + akq[i]);
        if (PE) pe_add4(pa[i], (bm + am[i]) & (TT - 1), akq[i]);
        pb[i] = *(const f32x4*)(Bm + (size_t)bkr[i] * N + bn + bnq[i]);
    }

    int buf = 0;
    for (int k0i = 0; ; k0i++) {
        #pragma unroll
        for (int i = 0; i < 4; i++) {
            #pragma unroll
            for (int j = 0; j < 4; j++) As[buf][akq[i] + j][am[i]] = pa[i][j];
            *(f32x4*)&Bs[buf][bkr[i]][bnq[i]] = pb[i];
        }
        __syncthreads();            // single barrier per K-step (dbuf)
        if (k0i + 1 < nk0) {
            int k0 = (k0i + 1) * 32;
            #pragma unroll
            for (int i = 0; i < 4; i++) {
                pa[i] = *(const f32x4*)(A + (size_t)(bm + am[i]) * K + k0 + akq[i]);
                if (PE) pe_add4(pa[i], (bm + am[i]) & (TT - 1), k0 + akq[i]);
                pb[i] = *(const f32x4*)(Bm + (size_t)(k0 + bkr[i]) * N + bn + bnq[i]);
            }
        }
        #pragma unroll 4
        for (int kk = 0; kk < 32; kk++) {
            f32x4 a0 = *(const f32x4*)&As[buf][kk][ty * 8];
            f32x4 a1 = *(const f32x4*)&As[buf][kk][ty * 8 + 4];
            f32x4 b0 = *(const f32x4*)&Bs[buf][kk][tx * 4];
            f32x4 b1 = *(const f32x4*)&Bs[buf][kk][64 + tx * 4];
            #pragma unroll
            for (int i2 = 0; i2 < 4; i2++)
                #pragma unroll
                for (int j2 = 0; j2 < 4; j2++) {
                    acc[i2][j2]         += a0[i2] * b0[j2];
                    acc[i2][j2 + 4]     += a0[i2] * b1[j2];
                    acc[i2 + 4][j2]     += a1[i2] * b0[j2];
                    acc[i2 + 4][j2 + 4] += a1[i2] * b1[j2];
                }
        }
        buf ^= 1;
        if (k0i + 1 == nk0) break;
    }

    #pragma unroll
    for (int i = 0; i < 8; i++) {
        int gm = bm + ty * 8 + i;
        f32x4 o0, o1;
        #pragma unroll
        for (int j = 0; j < 4; j++) {
            float v0 = acc[i][j]     + bias[bn + tx * 4 + j];
            float v1 = acc[i][j + 4] + bias[bn + 64 + tx * 4 + j];
            if (do_relu) { v0 = fmaxf(v0, 0.f); v1 = fmaxf(v1, 0.f); }
            o0[j] = v0; o1[j] = v1;
        }
        *(f32x4*)(Cm + (size_t)gm * N + bn + tx * 4)      = o0;
        *(f32x4*)(Cm + (size_t)gm * N + bn + 64 + tx * 4) = o1;
    }
}

// ---------------------------------------------------------------------------
// q + PE  (argmax-frozen)
// ---------------------------------------------------------------------------
__global__ void qpe_kernel(const float* __restrict__ q, float* __restrict__ out)
{
    int idx = blockIdx.x * 256 + threadIdx.x;
    if (idx >= BB * NWW * QQ) return;
    int qi = idx % QQ;
    int w  = (idx / QQ) % NWW;
    float di = expf((float)(qi & ~1) * (-9.210340371976184f / (float)QQ));
    float ang = (float)w * di;
    out[idx] = q[idx] + ((qi & 1) ? cosf(ang) : sinf(ang));
}

// ---------------------------------------------------------------------------
// Dual small GEMM with per-head A/W/C (blockIdx.y = head). Per output the
// PROVEN bit-identical strict ascending-k fmaf chain with group-10 prefetch
// (== sgemm_exact / R6). One output per thread, 64-thread blocks ->
// 600-1024 blocks/launch: the R9 fusion regression showed this shape wins.
// ---------------------------------------------------------------------------
__global__ __launch_bounds__(64) void sgemm_dual2(
    const float* __restrict__ A1, const float* __restrict__ W1,
    const float* __restrict__ b1, float* __restrict__ C1,
    const float* __restrict__ A2, const float* __restrict__ W2,
    const float* __restrict__ b2, float* __restrict__ C2,
    int M, int N, int K, int do_relu)
{
    int id = blockIdx.x * 64 + threadIdx.x;
    if (id >= M * N) return;
    const float* A = blockIdx.y ? A2 : A1;
    const float* B = blockIdx.y ? W2 : W1;
    const float* bias = blockIdx.y ? b2 : b1;
    float* C = blockIdx.y ? C2 : C1;
    int m = id / N, n = id % N;
    const float* a = A + (size_t)m * K;
    const float* b = B + n;
    float acc = 0.f;
    int k = 0;
    for (; k + 10 <= K; k += 10) {
        float av[10], bv[10];
        #pragma unroll
        for (int u = 0; u < 10; u++) av[u] = a[k + u];
        #pragma unroll
        for (int u = 0; u < 10; u++) bv[u] = b[(size_t)(k + u) * N];
        #pragma unroll
        for (int u = 0; u < 10; u++) acc = fmaf(av[u], bv[u], acc);
    }
    for (; k < K; k++) acc = fmaf(a[k], b[(size_t)k * N], acc);
    float val = acc + bias[n];
    if (do_relu) val = fmaxf(val, 0.f);
    C[id] = val;
}

// ---------------------------------------------------------------------------
// bf16 MFMA GEMM (continuous-output path only): unchanged from R3.
// ---------------------------------------------------------------------------
__global__ __launch_bounds__(256) void gemm_bf16_kernel(
    const short* __restrict__ A,   // [M,K] bf16 bits
    const short* __restrict__ Bt,  // [N,K] bf16 bits
    const float* __restrict__ bias, float* __restrict__ C,
    int M, int N, int K, int do_relu)
{
    __shared__ short As[128][40];
    __shared__ short Bs[128][40];
    const int bm = blockIdx.x * 128;
    const int bn = blockIdx.y * 128;
    const int tid = threadIdx.x;
    const int wave = tid >> 6, lane = tid & 63;
    const int wm = (wave & 1) * 64, wn = (wave >> 1) * 64;
    const int l15 = lane & 15, lk = (lane >> 4) * 8;
    const int srow = tid >> 2;
    const int scol = (tid & 3) * 8;

    f32x4 acc[4][4] = {};

    for (int k0 = 0; k0 < K; k0 += 32) {
        #pragma unroll
        for (int p = 0; p < 2; p++) {
            int row = p * 64 + srow;
            short8 av = {};
            int gm = bm + row;
            if (gm < M) av = *(const short8*)(A + (size_t)gm * K + k0 + scol);
            *(short8*)&As[row][scol] = av;
            short8 bv = {};
            int gn = bn + row;
            if (gn < N) bv = *(const short8*)(Bt + (size_t)gn * K + k0 + scol);
            *(short8*)&Bs[row][scol] = bv;
        }
        __syncthreads();

        short8 af[4], bf[4];
        #pragma unroll
        for (int mi = 0; mi < 4; mi++)
            af[mi] = *(const short8*)&As[wm + mi * 16 + l15][lk];
        #pragma unroll
        for (int ni = 0; ni < 4; ni++)
            bf[ni] = *(const short8*)&Bs[wn + ni * 16 + l15][lk];
        #pragma unroll
        for (int mi = 0; mi < 4; mi++)
            #pragma unroll
            for (int ni = 0; ni < 4; ni++)
                acc[mi][ni] = __builtin_amdgcn_mfma_f32_16x16x32_bf16(
                    af[mi], bf[ni], acc[mi][ni], 0, 0, 0);
        __syncthreads();
    }

    #pragma unroll
    for (int mi = 0; mi < 4; mi++) {
        int row0 = bm + wm + mi * 16 + (lane >> 4) * 4;
        #pragma unroll
        for (int ni = 0; ni < 4; ni++) {
            int col = bn + wn + ni * 16 + l15;
            float bsv = bias ? bias[col] : 0.f;
            #pragma unroll
            for (int r = 0; r < 4; r++) {
                int grow = row0 + r;
                if (grow >= M) continue;
                float val = acc[mi][ni][r] + bsv;
                if (do_relu) val = fmaxf(val, 0.f);
                C[(size_t)grow * N + col] = val;
            }
        }
    }
}

// ---------------------------------------------------------------------------
// LDS-tiled transpose+convert: dst[n][k] = bf16(src[k][n]). K,N % 32 == 0.
// ---------------------------------------------------------------------------
__global__ __launch_bounds__(256) void convT2_kernel(
    const float* __restrict__ src, __hip_bfloat16* __restrict__ dst,
    int K, int N)
{
    __shared__ float t[32][33];
    int c = threadIdx.x & 31, r4 = threadIdx.x >> 5;   // 32 x 8
    int n0 = blockIdx.x * 32, k0 = blockIdx.y * 32;
    #pragma unroll
    for (int rr = 0; rr < 32; rr += 8)
        t[rr + r4][c] = src[(size_t)(k0 + rr + r4) * N + n0 + c];
    __syncthreads();
    #pragma unroll
    for (int rr = 0; rr < 32; rr += 8)
        dst[(size_t)(n0 + rr + r4) * K + k0 + c] = __float2bfloat16(t[c][rr + r4]);
}

// ---------------------------------------------------------------------------
// sim[b,t,w] = sum_c v[b,t,c] * enc1[b,w,c]   (bit-identical chain)
// ---------------------------------------------------------------------------
__global__ __launch_bounds__(256) void sim_kernel(
    const float* __restrict__ v, const float* __restrict__ enc1,
    float* __restrict__ sim)
{
    __shared__ float vs[8][CC];
    int blk = blockIdx.x;
    int b  = blk / (TT / 8);
    int t0 = (blk % (TT / 8)) * 8;
    int tid = threadIdx.x;
    for (int i = tid; i < 8 * (CC / 4); i += 256) {
        int r = i / (CC / 4), c = i % (CC / 4);
        *(f32x4*)&vs[r][c * 4] =
            *(const f32x4*)(v + ((size_t)b * TT + t0 + r) * CC + c * 4);
    }
    __syncthreads();
    int w  = tid & 31;
    int tt = tid >> 5;
    const f32x4* e4 = (const f32x4*)(enc1 + ((size_t)b * NWW + w) * CC);
    const f32x4* v4 = (const f32x4*)vs[tt];
    float s = 0.f;
    #pragma unroll 4
    for (int kq = 0; kq < CC / 4; kq++) {
        f32x4 vv = v4[kq], ee = e4[kq];
        s = fmaf(vv[0], ee[0], s);
        s = fmaf(vv[1], ee[1], s);
        s = fmaf(vv[2], ee[2], s);
        s = fmaf(vv[3], ee[3], s);
    }
    sim[((size_t)b * TT + t0 + tt) * NWW + w] = s;
}

// ---------------------------------------------------------------------------
// pu[b,t,:] = 0.25*(((v[t]+v[t+1])+v[t+2])+v[t+3])  — expression verbatim.
// ---------------------------------------------------------------------------
__global__ __launch_bounds__(256) void pu_kernel(
    const float* __restrict__ v, float* __restrict__ pu)
{
    int idx = blockIdx.x * 256 + threadIdx.x;     // over B*PUL*(C/4)
    if (idx >= BB * PUL * (CC / 4)) return;
    int q = idx % (CC / 4);
    int t = (idx / (CC / 4)) % PUL;
    int b = idx / ((CC / 4) * PUL);
    const float* vp = v + ((size_t)b * TT + t) * CC + q * 4;
    f32x4 r0 = *(const f32x4*)vp;
    f32x4 r1 = *(const f32x4*)(vp + CC);
    f32x4 r2 = *(const f32x4*)(vp + 2 * CC);
    f32x4 r3 = *(const f32x4*)(vp + 3 * CC);
    f32x4 o;
    #pragma unroll
    for (int j = 0; j < 4; j++)
        o[j] = 0.25f * (((r0[j] + r1[j]) + r2[j]) + r3[j]);
    *(f32x4*)(pu + ((size_t)b * PUL + t) * CC + q * 4) = o;
}

// ---------------------------------------------------------------------------
// Per (b,l): bel argmax (VERBATIM frozen code) + gather + modulate via pu
// ---------------------------------------------------------------------------
__global__ __launch_bounds__(256) void mod_kernel(
    const float* __restrict__ pu, const float* __restrict__ sim,
    const float* __restrict__ enc2, __hip_bfloat16* __restrict__ modb)
{
    int blk = blockIdx.x;                  // b*L + l
    int b = blk / LL, l = blk % LL;
    int tid = threadIdx.x;
    int cch = tid >> 6;
    int lane = tid & 63;
    int t0 = l + cch * 4;

    int w = lane & 31;
    const float* sp = sim + ((size_t)b * TT + t0) * NWW + w;
    float bel = sp[0] + sp[NWW] + sp[2 * NWW] + sp[3 * NWW];
    int idx = w;
    #pragma unroll
    for (int m = 1; m < 32; m <<= 1) {
        float ov = __shfl_xor(bel, m);
        int   oi = __shfl_xor(idx, m);
        if (ov > bel || (ov == bel && oi < idx)) { bel = ov; idx = oi; }
    }

    const f32x4* e2 = (const f32x4*)(enc2 + ((size_t)b * NWW + idx) * CC);
    const f32x4* pq = (const f32x4*)(pu + ((size_t)b * PUL + t0) * CC);
    __hip_bfloat16* mp = modb + (((size_t)blk) * NCC + cch) * CC;
    #pragma unroll
    for (int q = lane; q < CC / 4; q += 64) {
        f32x4 e = e2[q], p = pq[q];
        short4v o;
        #pragma unroll
        for (int j = 0; j < 4; j++) {
            __hip_bfloat16 h = __float2bfloat16(e[j] * p[j]);
            o[j] = *(short*)&h;
        }
        *(short4v*)(mp + q * 4) = o;
    }
}

// ---------------------------------------------------------------------------
// pred head 2, wave-parallel: one wave per row, both outputs.
// ---------------------------------------------------------------------------
__global__ __launch_bounds__(256) void pred2w_kernel(
    const float* __restrict__ hpred, const float* __restrict__ pW2,
    const float* __restrict__ pb2, float* __restrict__ out)
{
    int row = blockIdx.x * 4 + (threadIdx.x >> 6);
    if (row >= BB * LL) return;
    int lane = threadIdx.x & 63;
    const float* h = hpred + (size_t)row * CC + lane * 8;
    f32x4 h0 = *(const f32x4*)h;
    f32x4 h1 = *(const f32x4*)(h + 4);
    const float* wp = pW2 + lane * 16;
    f32x4 w0 = *(const f32x4*)wp;
    f32x4 w1 = *(const f32x4*)(wp + 4);
    f32x4 w2 = *(const f32x4*)(wp + 8);
    f32x4 w3 = *(const f32x4*)(wp + 12);
    float s0 = h0[0]*w0[0] + h0[1]*w0[2] + h0[2]*w1[0] + h0[3]*w1[2]
             + h1[0]*w2[0] + h1[1]*w2[2] + h1[2]*w3[0] + h1[3]*w3[2];
    float s1 = h0[0]*w0[1] + h0[1]*w0[3] + h0[2]*w1[1] + h0[3]*w1[3]
             + h1[0]*w2[1] + h1[1]*w2[3] + h1[2]*w3[1] + h1[3]*w3[3];
    #pragma unroll
    for (int m = 32; m; m >>= 1) {
        s0 += __shfl_xor(s0, m);
        s1 += __shfl_xor(s1, m);
    }
    if (lane == 0) {
        int b = row / LL, l = row % LL;
        out[((size_t)b * 2 + 0) * LL + l] = s0 + pb2[0];
        out[((size_t)b * 2 + 1) * LL + l] = s1 + pb2[1];
    }
}

// ---------------------------------------------------------------------------
// ragged adaptive max-pool, two-stage (max is exactly associative)
// ---------------------------------------------------------------------------
__global__ __launch_bounds__(256) void pool1_kernel(
    const float* __restrict__ x, const int* __restrict__ vis_len,
    float* __restrict__ scratch)
{
    int blk = blockIdx.x;             // ((b*SS + s)*NSUB + sub)
    int sub = blk % NSUB;
    int s   = (blk / NSUB) % SS;
    int b   = blk / (NSUB * SS);
    int n = vis_len[b] * NCC;
    int st = (n * s) / SS;
    int en = (n * (s + 1) + SS - 1) / SS;
    int len = en - st;
    int j0 = st + (len * sub) / NSUB;
    int j1 = st + (len * (sub + 1)) / NSUB;
    int md = threadIdx.x;
    float m = -INFINITY;
    const float* xp = x + (size_t)b * (LL * NCC) * MDD + md;
    for (int j = j0; j < j1; j++) m = fmaxf(m, xp[(size_t)j * MDD]);
    scratch[(size_t)blk * MDD + md] = m;
}

__global__ __launch_bounds__(256) void pool2_kernel(
    const float* __restrict__ scratch, float* __restrict__ feat)
{
    int blk = blockIdx.x;  // b*SS + s
    int md = threadIdx.x;
    const float* sp = scratch + (size_t)blk * NSUB * MDD + md;
    float m = sp[0];
    #pragma unroll
    for (int i = 1; i < NSUB; i++) m = fmaxf(m, sp[(size_t)i * MDD]);
    int b = blk / SS, s = blk % SS;
    feat[(size_t)b * MDD * SS + md * SS + s] = m;
}

// ---------------------------------------------------------------------------
// start/end heads
// ---------------------------------------------------------------------------
__global__ void stend_kernel(const float* __restrict__ feat,
                             const float* __restrict__ stW, const float* __restrict__ stb,
                             const float* __restrict__ enW, const float* __restrict__ enb,
                             float* __restrict__ out)
{
    int bid = blockIdx.x;                  // 0..127
    int which = bid >> 6;
    int r = bid & 63;
    int b = r >> 4, s = r & 15;
    int lane = threadIdx.x;                // 64
    const float* W  = which ? enW : stW;
    const float* bb = which ? enb : stb;
    const float* f  = feat + (size_t)b * MDD * SS;
    float acc = 0.f;
    for (int k = lane; k < MDD * SS; k += 64) acc += f[k] * W[(size_t)k * SS + s];
    #pragma unroll
    for (int m = 32; m; m >>= 1) acc += __shfl_xor(acc, m);
    if (lane == 0)
        out[(size_t)BB * 2 * LL + which * (BB * SS) + b * SS + s] = acc + bb[s];
}

// ---------------------------------------------------------------------------
extern "C" void kernel_launch(void* const* d_in, const int* in_sizes, int n_in,
                              void* d_out, int out_size, void* d_ws, size_t ws_size,
                              hipStream_t stream)
{
    const float* vis  = (const float*)d_in[0];
    const float* qf   = (const float*)d_in[1];
    const float* vW1  = (const float*)d_in[2];  const float* vb1 = (const float*)d_in[3];
    const float* vW2  = (const float*)d_in[4];  const float* vb2 = (const float*)d_in[5];
    const float* s1W1 = (const float*)d_in[6];  const float* s1b1= (const float*)d_in[7];
    const float* s1W2 = (const float*)d_in[8];  const float* s1b2= (const float*)d_in[9];
    const float* s2W1 = (const float*)d_in[10]; const float* s2b1= (const float*)d_in[11];
    const float* s2W2 = (const float*)d_in[12]; const float* s2b2= (const float*)d_in[13];
    const float* pW1  = (const float*)d_in[14]; const float* pb1 = (const float*)d_in[15];
    const float* pW2  = (const float*)d_in[16]; const float* pb2 = (const float*)d_in[17];
    const float* mW   = (const float*)d_in[18]; const float* mb  = (const float*)d_in[19];
    const float* stW  = (const float*)d_in[20]; const float* stb = (const float*)d_in[21];
    const float* enW  = (const float*)d_in[22]; const float* enb = (const float*)d_in[23];
    const int*   vlen = (const int*)d_in[24];
    float* out = (float*)d_out;

    // workspace layout (floats; 16B-aligned blocks)
    float* ws   = (float*)d_ws;
    float* h1   = ws;                                 // B*T*C (reused: pu, then hpred)
    float* v    = h1   + (size_t)BB * TT * CC;        // B*T*C
    float* qpe  = v    + (size_t)BB * TT * CC;        // B*NW*Q
    float* qh   = qpe  + (size_t)BB * NWW * QQ;       // B*NW*Q  (qh1)
    float* enc1 = qh   + (size_t)BB * NWW * QQ;       // B*NW*C
    float* enc2 = enc1 + (size_t)BB * NWW * CC;       // B*NW*C
    float* sim  = enc2 + (size_t)BB * NWW * CC;       // B*T*NW (reused as pool scratch)
    float* feat = sim  + (size_t)BB * TT * NWW;       // B*MD*S
    float* x    = feat + (size_t)BB * MDD * SS;       // B*L*NC*MD
    float* fend = x    + (size_t)BB * LL * NCC * MDD;
    __hip_bfloat16* modb = (__hip_bfloat16*)fend;                  // MX*C bf16
    __hip_bfloat16* pW1t = modb + (size_t)BB * LL * NCC * CC;      // 512*2048 bf16
    __hip_bfloat16* mWt  = pW1t + (size_t)CC * (NCC * CC);         // 256*512 bf16
    float* qh2 = (float*)(mWt + (size_t)CC * MDD);                 // B*NW*Q (qh2)

    const int MT = BB * TT;            // 8192
    const int ML = BB * LL;            // 8132
    const int MX = BB * LL * NCC;      // 32528

    // weight convert+transpose (bf16), LDS-tiled
    convT2_kernel<<<dim3(CC / 32, (NCC * CC) / 32), 256, 0, stream>>>(pW1, pW1t, NCC * CC, CC);
    convT2_kernel<<<dim3(MDD / 32, CC / 32), 256, 0, stream>>>(mW, mWt, CC, MDD);

    // 1. h1 = relu(PE(vis) @ vW1 + vb1)   (fp32 — bit-identical values)
    gemm_f32_fast<1><<<dim3(MT / 128, CC / 128), 256, 0, stream>>>(
        vis, vW1, vb1, h1, MT, CC, CC, 1);
    // 2. v = h1 @ vW2 + vb2
    gemm_f32_fast<0><<<dim3(MT / 128, CC / 128), 256, 0, stream>>>(
        h1, vW2, vb2, v, MT, CC, CC, 0);
    // 3. qpe (argmax-frozen)
    qpe_kernel<<<(BB * NWW * QQ + 255) / 256, 256, 0, stream>>>(qf, qpe);
    // 4-5. query layer 1, both heads (one launch, 600x2 blocks)
    sgemm_dual2<<<dim3((BB * NWW * QQ + 63) / 64, 2), 64, 0, stream>>>(
        qpe, s1W1, s1b1, qh, qpe, s2W1, s2b1, qh2, BB * NWW, QQ, QQ, 1);
    // 6-7. query layer 2, both heads (one launch, 1024x2 blocks)
    sgemm_dual2<<<dim3((BB * NWW * CC + 63) / 64, 2), 64, 0, stream>>>(
        qh, s1W2, s1b2, enc1, qh2, s2W2, s2b2, enc2, BB * NWW, CC, QQ, 0);
    // 8. sim
    sim_kernel<<<BB * (TT / 8), 256, 0, stream>>>(v, enc1, sim);
    // 8b. pu into h1 (dead until step 11)
    pu_kernel<<<(BB * PUL * (CC / 4) + 255) / 256, 256, 0, stream>>>(v, h1);
    // 9. mod (argmax verbatim; modulate via pu)
    mod_kernel<<<BB * LL, 256, 0, stream>>>(h1, sim, enc2, modb);
    // 10. x = mod @ mW + mb   [MX, MD]  (bf16 MFMA)
    gemm_bf16_kernel<<<dim3((MX + 127) / 128, MDD / 128), 256, 0, stream>>>(
        (const short*)modb, (const short*)mWt, mb, x, MX, MDD, CC, 0);
    // 11. hpred = relu(mod @ pW1 + pb1)  [ML, C], K=2048 (bf16 MFMA; h1 reused)
    gemm_bf16_kernel<<<dim3((ML + 127) / 128, CC / 128), 256, 0, stream>>>(
        (const short*)modb, (const short*)pW1t, pb1, h1, ML, CC, NCC * CC, 1);
    // 12. pred head -> out (wave-parallel)
    pred2w_kernel<<<(ML + 3) / 4, 256, 0, stream>>>(h1, pW2, pb2, out);
    // 13. ragged adaptive max-pool, two-stage (sim buffer reused as scratch)
    pool1_kernel<<<BB * SS * NSUB, 256, 0, stream>>>(x, vlen, sim);
    pool2_kernel<<<BB * SS, 256, 0, stream>>>(sim, feat);
    // 14. start/end heads
    stend_kernel<<<128, 64, 0, stream>>>(feat, stW, stb, enW, enb, out);
}

// Round 12
// 408.413 us; speedup vs baseline: 1.1379x; 1.0076x over previous
//
#include <hip/hip_runtime.h>
#include <hip/hip_bf16.h>
#include <math.h>

#define BB 4
#define TT 2048
#define CC 512
#define QQ 300
#define NWW 32
#define MDD 256
#define WSS 16
#define NCC 4
#define SS 16
#define LL (TT - WSS + 1)   // 2033
#define NSUB 8
#define PUL (TT - 3)        // 2045 pu rows per batch

typedef __attribute__((ext_vector_type(8))) short short8;
typedef __attribute__((ext_vector_type(4))) short short4v;
typedef __attribute__((ext_vector_type(4))) float f32x4;

// ---------------------------------------------------------------------------
// PE add — expression kept VERBATIM identical to the frozen path.
// ---------------------------------------------------------------------------
__device__ __forceinline__ void pe_add4(f32x4& v, int t, int gk0)
{
    #pragma unroll
    for (int j = 0; j < 4; j++) {
        int gk = gk0 + j;
        float di = expf((float)(gk & ~1) * (-9.210340371976184f / (float)CC));
        float ang = (float)t * di;
        v[j] += (gk & 1) ? cosf(ang) : sinf(ang);
    }
}

// ---------------------------------------------------------------------------
// fp32 GEMM for the v-path (steps 1,2). BIT-IDENTICAL VALUES: per output a
// single fp32 accumulator, k strictly ascending, one `acc += a*b` statement.
// R12: REVERTED to the R8 version (64x128 tile, BK=32, dbuf LDS, one barrier
// per K-step, 2 blocks/CU) — proven through the full harness incl. the
// post-timing determinism check. NOTE: the BK=16 variant (R11) passed first
// validation but DIVERGED across graph replays — do not reintroduce it.
// ---------------------------------------------------------------------------
template<int PE>
__global__ __launch_bounds__(256, 2) void gemm_f32_fast(
    const float* __restrict__ A, const float* __restrict__ Bm,
    const float* __restrict__ bias, float* __restrict__ Cm,
    int M, int N, int K, int do_relu)
{
    __shared__ float As[2][32][68];    // k-major, padded
    __shared__ float Bs[2][32][128];
    const int bm = blockIdx.x * 64;
    const int bn = blockIdx.y * 128;
    const int tid = threadIdx.x;
    const int tx = tid & 31;        // n-quad: n0 = tx*4
    const int ty = tid >> 5;        // m-oct: m0 = ty*8

    float acc[8][4] = {};
    f32x4 pa[2], pb[4];
    int am[2], akq[2], bkr[4], bnq[4];
    #pragma unroll
    for (int i = 0; i < 2; i++) {
        int idx = i * 256 + tid;
        am[i] = idx >> 3; akq[i] = (idx & 7) * 4;      // A: 64 rows x 32 k
    }
    #pragma unroll
    for (int i = 0; i < 4; i++) {
        int idx = i * 256 + tid;
        bkr[i] = idx >> 5; bnq[i] = (idx & 31) * 4;    // B: 32 k x 128 n
    }

    const int nk0 = K / 32;
    #pragma unroll
    for (int i = 0; i < 2; i++) {
        pa[i] = *(const f32x4*)(A + (size_t)(bm + am[i]) * K + akq[i]);
        if (PE) pe_add4(pa[i], (bm + am[i]) & (TT - 1), akq[i]);
    }
    #pragma unroll
    for (int i = 0; i < 4; i++)
        pb[i] = *(const f32x4*)(Bm + (size_t)bkr[i] * N + bn + bnq[i]);

    int buf = 0;
    for (int k0i = 0; ; k0i++) {
        #pragma unroll
        for (int i = 0; i < 2; i++)
            #pragma unroll
            for (int j = 0; j < 4; j++) As[buf][akq[i] + j][am[i]] = pa[i][j];
        #pragma unroll
        for (int i = 0; i < 4; i++)
            *(f32x4*)&Bs[buf][bkr[i]][bnq[i]] = pb[i];
        __syncthreads();            // single barrier per K-step (dbuf)
        if (k0i + 1 < nk0) {
            int k0 = (k0i + 1) * 32;
            #pragma unroll
            for (int i = 0; i < 2; i++) {
                pa[i] = *(const f32x4*)(A + (size_t)(bm + am[i]) * K + k0 + akq[i]);
                if (PE) pe_add4(pa[i], (bm + am[i]) & (TT - 1), k0 + akq[i]);
            }
            #pragma unroll
            for (int i = 0; i < 4; i++)
                pb[i] = *(const f32x4*)(Bm + (size_t)(k0 + bkr[i]) * N + bn + bnq[i]);
        }
        #pragma unroll 8
        for (int kk = 0; kk < 32; kk++) {
            f32x4 a0 = *(const f32x4*)&As[buf][kk][ty * 8];
            f32x4 a1 = *(const f32x4*)&As[buf][kk][ty * 8 + 4];
            f32x4 b0 = *(const f32x4*)&Bs[buf][kk][tx * 4];
            #pragma unroll
            for (int i2 = 0; i2 < 4; i2++)
                #pragma unroll
                for (int j2 = 0; j2 < 4; j2++) {
                    acc[i2][j2]     += a0[i2] * b0[j2];
                    acc[i2 + 4][j2] += a1[i2] * b0[j2];
                }
        }
        buf ^= 1;
        if (k0i + 1 == nk0) break;
    }

    #pragma unroll
    for (int i = 0; i < 8; i++) {
        int gm = bm + ty * 8 + i;
        f32x4 o;
        #pragma unroll
        for (int j = 0; j < 4; j++) {
            float v0 = acc[i][j] + bias[bn + tx * 4 + j];
            if (do_relu) v0 = fmaxf(v0, 0.f);
            o[j] = v0;
        }
        *(f32x4*)(Cm + (size_t)gm * N + bn + tx * 4) = o;
    }
}

// ---------------------------------------------------------------------------
// q + PE  (argmax-frozen)
// ---------------------------------------------------------------------------
__global__ void qpe_kernel(const float* __restrict__ q, float* __restrict__ out)
{
    int idx = blockIdx.x * 256 + threadIdx.x;
    if (idx >= BB * NWW * QQ) return;
    int qi = idx % QQ;
    int w  = (idx / QQ) % NWW;
    float di = expf((float)(qi & ~1) * (-9.210340371976184f / (float)QQ));
    float ang = (float)w * di;
    out[idx] = q[idx] + ((qi & 1) ? cosf(ang) : sinf(ang));
}

// ---------------------------------------------------------------------------
// Dual small GEMM with per-head A/W/C (blockIdx.y = head). Per output the
// PROVEN bit-identical strict ascending-k fmaf chain with group-10 prefetch.
// One output per thread, 64-thread blocks (R9 showed fusion loses).
// ---------------------------------------------------------------------------
__global__ __launch_bounds__(64) void sgemm_dual2(
    const float* __restrict__ A1, const float* __restrict__ W1,
    const float* __restrict__ b1, float* __restrict__ C1,
    const float* __restrict__ A2, const float* __restrict__ W2,
    const float* __restrict__ b2, float* __restrict__ C2,
    int M, int N, int K, int do_relu)
{
    int id = blockIdx.x * 64 + threadIdx.x;
    if (id >= M * N) return;
    const float* A = blockIdx.y ? A2 : A1;
    const float* B = blockIdx.y ? W2 : W1;
    const float* bias = blockIdx.y ? b2 : b1;
    float* C = blockIdx.y ? C2 : C1;
    int m = id / N, n = id % N;
    const float* a = A + (size_t)m * K;
    const float* b = B + n;
    float acc = 0.f;
    int k = 0;
    for (; k + 10 <= K; k += 10) {
        float av[10], bv[10];
        #pragma unroll
        for (int u = 0; u < 10; u++) av[u] = a[k + u];
        #pragma unroll
        for (int u = 0; u < 10; u++) bv[u] = b[(size_t)(k + u) * N];
        #pragma unroll
        for (int u = 0; u < 10; u++) acc = fmaf(av[u], bv[u], acc);
    }
    for (; k < K; k++) acc = fmaf(a[k], b[(size_t)k * N], acc);
    float val = acc + bias[n];
    if (do_relu) val = fmaxf(val, 0.f);
    C[id] = val;
}

// ---------------------------------------------------------------------------
// bf16 MFMA GEMM (continuous-output path only): unchanged from R3.
// ---------------------------------------------------------------------------
__global__ __launch_bounds__(256) void gemm_bf16_kernel(
    const short* __restrict__ A,   // [M,K] bf16 bits
    const short* __restrict__ Bt,  // [N,K] bf16 bits
    const float* __restrict__ bias, float* __restrict__ C,
    int M, int N, int K, int do_relu)
{
    __shared__ short As[128][40];
    __shared__ short Bs[128][40];
    const int bm = blockIdx.x * 128;
    const int bn = blockIdx.y * 128;
    const int tid = threadIdx.x;
    const int wave = tid >> 6, lane = tid & 63;
    const int wm = (wave & 1) * 64, wn = (wave >> 1) * 64;
    const int l15 = lane & 15, lk = (lane >> 4) * 8;
    const int srow = tid >> 2;
    const int scol = (tid & 3) * 8;

    f32x4 acc[4][4] = {};

    for (int k0 = 0; k0 < K; k0 += 32) {
        #pragma unroll
        for (int p = 0; p < 2; p++) {
            int row = p * 64 + srow;
            short8 av = {};
            int gm = bm + row;
            if (gm < M) av = *(const short8*)(A + (size_t)gm * K + k0 + scol);
            *(short8*)&As[row][scol] = av;
            short8 bv = {};
            int gn = bn + row;
            if (gn < N) bv = *(const short8*)(Bt + (size_t)gn * K + k0 + scol);
            *(short8*)&Bs[row][scol] = bv;
        }
        __syncthreads();

        short8 af[4], bf[4];
        #pragma unroll
        for (int mi = 0; mi < 4; mi++)
            af[mi] = *(const short8*)&As[wm + mi * 16 + l15][lk];
        #pragma unroll
        for (int ni = 0; ni < 4; ni++)
            bf[ni] = *(const short8*)&Bs[wn + ni * 16 + l15][lk];
        #pragma unroll
        for (int mi = 0; mi < 4; mi++)
            #pragma unroll
            for (int ni = 0; ni < 4; ni++)
                acc[mi][ni] = __builtin_amdgcn_mfma_f32_16x16x32_bf16(
                    af[mi], bf[ni], acc[mi][ni], 0, 0, 0);
        __syncthreads();
    }

    #pragma unroll
    for (int mi = 0; mi < 4; mi++) {
        int row0 = bm + wm + mi * 16 + (lane >> 4) * 4;
        #pragma unroll
        for (int ni = 0; ni < 4; ni++) {
            int col = bn + wn + ni * 16 + l15;
            float bsv = bias ? bias[col] : 0.f;
            #pragma unroll
            for (int r = 0; r < 4; r++) {
                int grow = row0 + r;
                if (grow >= M) continue;
                float val = acc[mi][ni][r] + bsv;
                if (do_relu) val = fmaxf(val, 0.f);
                C[(size_t)grow * N + col] = val;
            }
        }
    }
}

// ---------------------------------------------------------------------------
// LDS-tiled transpose+convert: dst[n][k] = bf16(src[k][n]). K,N % 32 == 0.
// ---------------------------------------------------------------------------
__global__ __launch_bounds__(256) void convT2_kernel(
    const float* __restrict__ src, __hip_bfloat16* __restrict__ dst,
    int K, int N)
{
    __shared__ float t[32][33];
    int c = threadIdx.x & 31, r4 = threadIdx.x >> 5;   // 32 x 8
    int n0 = blockIdx.x * 32, k0 = blockIdx.y * 32;
    #pragma unroll
    for (int rr = 0; rr < 32; rr += 8)
        t[rr + r4][c] = src[(size_t)(k0 + rr + r4) * N + n0 + c];
    __syncthreads();
    #pragma unroll
    for (int rr = 0; rr < 32; rr += 8)
        dst[(size_t)(n0 + rr + r4) * K + k0 + c] = __float2bfloat16(t[c][rr + r4]);
}

// ---------------------------------------------------------------------------
// sim[b,t,w] = sum_c v[b,t,c] * enc1[b,w,c]   (bit-identical chain)
// ---------------------------------------------------------------------------
__global__ __launch_bounds__(256) void sim_kernel(
    const float* __restrict__ v, const float* __restrict__ enc1,
    float* __restrict__ sim)
{
    __shared__ float vs[8][CC];
    int blk = blockIdx.x;
    int b  = blk / (TT / 8);
    int t0 = (blk % (TT / 8)) * 8;
    int tid = threadIdx.x;
    for (int i = tid; i < 8 * (CC / 4); i += 256) {
        int r = i / (CC / 4), c = i % (CC / 4);
        *(f32x4*)&vs[r][c * 4] =
            *(const f32x4*)(v + ((size_t)b * TT + t0 + r) * CC + c * 4);
    }
    __syncthreads();
    int w  = tid & 31;
    int tt = tid >> 5;
    const f32x4* e4 = (const f32x4*)(enc1 + ((size_t)b * NWW + w) * CC);
    const f32x4* v4 = (const f32x4*)vs[tt];
    float s = 0.f;
    #pragma unroll 4
    for (int kq = 0; kq < CC / 4; kq++) {
        f32x4 vv = v4[kq], ee = e4[kq];
        s = fmaf(vv[0], ee[0], s);
        s = fmaf(vv[1], ee[1], s);
        s = fmaf(vv[2], ee[2], s);
        s = fmaf(vv[3], ee[3], s);
    }
    sim[((size_t)b * TT + t0 + tt) * NWW + w] = s;
}

// ---------------------------------------------------------------------------
// pu[b,t,:] = 0.25*(((v[t]+v[t+1])+v[t+2])+v[t+3])  — expression verbatim.
// ---------------------------------------------------------------------------
__global__ __launch_bounds__(256) void pu_kernel(
    const float* __restrict__ v, float* __restrict__ pu)
{
    int idx = blockIdx.x * 256 + threadIdx.x;     // over B*PUL*(C/4)
    if (idx >= BB * PUL * (CC / 4)) return;
    int q = idx % (CC / 4);
    int t = (idx / (CC / 4)) % PUL;
    int b = idx / ((CC / 4) * PUL);
    const float* vp = v + ((size_t)b * TT + t) * CC + q * 4;
    f32x4 r0 = *(const f32x4*)vp;
    f32x4 r1 = *(const f32x4*)(vp + CC);
    f32x4 r2 = *(const f32x4*)(vp + 2 * CC);
    f32x4 r3 = *(const f32x4*)(vp + 3 * CC);
    f32x4 o;
    #pragma unroll
    for (int j = 0; j < 4; j++)
        o[j] = 0.25f * (((r0[j] + r1[j]) + r2[j]) + r3[j]);
    *(f32x4*)(pu + ((size_t)b * PUL + t) * CC + q * 4) = o;
}

// ---------------------------------------------------------------------------
// Per (b,l): bel argmax (VERBATIM frozen code) + gather + modulate via pu
// ---------------------------------------------------------------------------
__global__ __launch_bounds__(256) void mod_kernel(
    const float* __restrict__ pu, const float* __restrict__ sim,
    const float* __restrict__ enc2, __hip_bfloat16* __restrict__ modb)
{
    int blk = blockIdx.x;                  // b*L + l
    int b = blk / LL, l = blk % LL;
    int tid = threadIdx.x;
    int cch = tid >> 6;
    int lane = tid & 63;
    int t0 = l + cch * 4;

    int w = lane & 31;
    const float* sp = sim + ((size_t)b * TT + t0) * NWW + w;
    float bel = sp[0] + sp[NWW] + sp[2 * NWW] + sp[3 * NWW];
    int idx = w;
    #pragma unroll
    for (int m = 1; m < 32; m <<= 1) {
        float ov = __shfl_xor(bel, m);
        int   oi = __shfl_xor(idx, m);
        if (ov > bel || (ov == bel && oi < idx)) { bel = ov; idx = oi; }
    }

    const f32x4* e2 = (const f32x4*)(enc2 + ((size_t)b * NWW + idx) * CC);
    const f32x4* pq = (const f32x4*)(pu + ((size_t)b * PUL + t0) * CC);
    __hip_bfloat16* mp = modb + (((size_t)blk) * NCC + cch) * CC;
    #pragma unroll
    for (int q = lane; q < CC / 4; q += 64) {
        f32x4 e = e2[q], p = pq[q];
        short4v o;
        #pragma unroll
        for (int j = 0; j < 4; j++) {
            __hip_bfloat16 h = __float2bfloat16(e[j] * p[j]);
            o[j] = *(short*)&h;
        }
        *(short4v*)(mp + q * 4) = o;
    }
}

// ---------------------------------------------------------------------------
// pred head 2, wave-parallel: one wave per row, both outputs.
// ---------------------------------------------------------------------------
__global__ __launch_bounds__(256) void pred2w_kernel(
    const float* __restrict__ hpred, const float* __restrict__ pW2,
    const float* __restrict__ pb2, float* __restrict__ out)
{
    int row = blockIdx.x * 4 + (threadIdx.x >> 6);
    if (row >= BB * LL) return;
    int lane = threadIdx.x & 63;
    const float* h = hpred + (size_t)row * CC + lane * 8;
    f32x4 h0 = *(const f32x4*)h;
    f32x4 h1 = *(const f32x4*)(h + 4);
    const float* wp = pW2 + lane * 16;
    f32x4 w0 = *(const f32x4*)wp;
    f32x4 w1 = *(const f32x4*)(wp + 4);
    f32x4 w2 = *(const f32x4*)(wp + 8);
    f32x4 w3 = *(const f32x4*)(wp + 12);
    float s0 = h0[0]*w0[0] + h0[1]*w0[2] + h0[2]*w1[0] + h0[3]*w1[2]
             + h1[0]*w2[0] + h1[1]*w2[2] + h1[2]*w3[0] + h1[3]*w3[2];
    float s1 = h0[0]*w0[1] + h0[1]*w0[3] + h0[2]*w1[1] + h0[3]*w1[3]
             + h1[0]*w2[1] + h1[1]*w2[3] + h1[2]*w3[1] + h1[3]*w3[3];
    #pragma unroll
    for (int m = 32; m; m >>= 1) {
        s0 += __shfl_xor(s0, m);
        s1 += __shfl_xor(s1, m);
    }
    if (lane == 0) {
        int b = row / LL, l = row % LL;
        out[((size_t)b * 2 + 0) * LL + l] = s0 + pb2[0];
        out[((size_t)b * 2 + 1) * LL + l] = s1 + pb2[1];
    }
}

// ---------------------------------------------------------------------------
// ragged adaptive max-pool, two-stage (max is exactly associative)
// ---------------------------------------------------------------------------
__global__ __launch_bounds__(256) void pool1_kernel(
    const float* __restrict__ x, const int* __restrict__ vis_len,
    float* __restrict__ scratch)
{
    int blk = blockIdx.x;             // ((b*SS + s)*NSUB + sub)
    int sub = blk % NSUB;
    int s   = (blk / NSUB) % SS;
    int b   = blk / (NSUB * SS);
    int n = vis_len[b] * NCC;
    int st = (n * s) / SS;
    int en = (n * (s + 1) + SS - 1) / SS;
    int len = en - st;
    int j0 = st + (len * sub) / NSUB;
    int j1 = st + (len * (sub + 1)) / NSUB;
    int md = threadIdx.x;
    float m = -INFINITY;
    const float* xp = x + (size_t)b * (LL * NCC) * MDD + md;
    for (int j = j0; j < j1; j++) m = fmaxf(m, xp[(size_t)j * MDD]);
    scratch[(size_t)blk * MDD + md] = m;
}

__global__ __launch_bounds__(256) void pool2_kernel(
    const float* __restrict__ scratch, float* __restrict__ feat)
{
    int blk = blockIdx.x;  // b*SS + s
    int md = threadIdx.x;
    const float* sp = scratch + (size_t)blk * NSUB * MDD + md;
    float m = sp[0];
    #pragma unroll
    for (int i = 1; i < NSUB; i++) m = fmaxf(m, sp[(size_t)i * MDD]);
    int b = blk / SS, s = blk % SS;
    feat[(size_t)b * MDD * SS + md * SS + s] = m;
}

// ---------------------------------------------------------------------------
// start/end heads
// ---------------------------------------------------------------------------
__global__ void stend_kernel(const float* __restrict__ feat,
                             const float* __restrict__ stW, const float* __restrict__ stb,
                             const float* __restrict__ enW, const float* __restrict__ enb,
                             float* __restrict__ out)
{
    int bid = blockIdx.x;                  // 0..127
    int which = bid >> 6;
    int r = bid & 63;
    int b = r >> 4, s = r & 15;
    int lane = threadIdx.x;                // 64
    const float* W  = which ? enW : stW;
    const float* bb = which ? enb : stb;
    const float* f  = feat + (size_t)b * MDD * SS;
    float acc = 0.f;
    for (int k = lane; k < MDD * SS; k += 64) acc += f[k] * W[(size_t)k * SS + s];
    #pragma unroll
    for (int m = 32; m; m >>= 1) acc += __shfl_xor(acc, m);
    if (lane == 0)
        out[(size_t)BB * 2 * LL + which * (BB * SS) + b * SS + s] = acc + bb[s];
}

// ---------------------------------------------------------------------------
extern "C" void kernel_launch(void* const* d_in, const int* in_sizes, int n_in,
                              void* d_out, int out_size, void* d_ws, size_t ws_size,
                              hipStream_t stream)
{
    const float* vis  = (const float*)d_in[0];
    const float* qf   = (const float*)d_in[1];
    const float* vW1  = (const float*)d_in[2];  const float* vb1 = (const float*)d_in[3];
    const float* vW2  = (const float*)d_in[4];  const float* vb2 = (const float*)d_in[5];
    const float* s1W1 = (const float*)d_in[6];  const float* s1b1= (const float*)d_in[7];
    const float* s1W2 = (const float*)d_in[8];  const float* s1b2= (const float*)d_in[9];
    const float* s2W1 = (const float*)d_in[10]; const float* s2b1= (const float*)d_in[11];
    const float* s2W2 = (const float*)d_in[12]; const float* s2b2= (const float*)d_in[13];
    const float* pW1  = (const float*)d_in[14]; const float* pb1 = (const float*)d_in[15];
    const float* pW2  = (const float*)d_in[16]; const float* pb2 = (const float*)d_in[17];
    const float* mW   = (const float*)d_in[18]; const float* mb  = (const float*)d_in[19];
    const float* stW  = (const float*)d_in[20]; const float* stb = (const float*)d_in[21];
    const float* enW  = (const float*)d_in[22]; const float* enb = (const float*)d_in[23];
    const int*   vlen = (const int*)d_in[24];
    float* out = (float*)d_out;

    // workspace layout (floats; 16B-aligned blocks)
    float* ws   = (float*)d_ws;
    float* h1   = ws;                                 // B*T*C (reused: pu, then hpred)
    float* v    = h1   + (size_t)BB * TT * CC;        // B*T*C
    float* qpe  = v    + (size_t)BB * TT * CC;        // B*NW*Q
    float* qh   = qpe  + (size_t)BB * NWW * QQ;       // B*NW*Q  (qh1)
    float* enc1 = qh   + (size_t)BB * NWW * QQ;       // B*NW*C
    float* enc2 = enc1 + (size_t)BB * NWW * CC;       // B*NW*C
    float* sim  = enc2 + (size_t)BB * NWW * CC;       // B*T*NW (reused as pool scratch)
    float* feat = sim  + (size_t)BB * TT * NWW;       // B*MD*S
    float* x    = feat + (size_t)BB * MDD * SS;       // B*L*NC*MD
    float* fend = x    + (size_t)BB * LL * NCC * MDD;
    __hip_bfloat16* modb = (__hip_bfloat16*)fend;                  // MX*C bf16
    __hip_bfloat16* pW1t = modb + (size_t)BB * LL * NCC * CC;      // 512*2048 bf16
    __hip_bfloat16* mWt  = pW1t + (size_t)CC * (NCC * CC);         // 256*512 bf16
    float* qh2 = (float*)(mWt + (size_t)CC * MDD);                 // B*NW*Q (qh2)

    const int MT = BB * TT;            // 8192
    const int ML = BB * LL;            // 8132
    const int MX = BB * LL * NCC;      // 32528

    // weight convert+transpose (bf16), LDS-tiled
    convT2_kernel<<<dim3(CC / 32, (NCC * CC) / 32), 256, 0, stream>>>(pW1, pW1t, NCC * CC, CC);
    convT2_kernel<<<dim3(MDD / 32, CC / 32), 256, 0, stream>>>(mW, mWt, CC, MDD);

    // 1. h1 = relu(PE(vis) @ vW1 + vb1)   (fp32 — bit-identical values)
    gemm_f32_fast<1><<<dim3(MT / 64, CC / 128), 256, 0, stream>>>(
        vis, vW1, vb1, h1, MT, CC, CC, 1);
    // 2. v = h1 @ vW2 + vb2
    gemm_f32_fast<0><<<dim3(MT / 64, CC / 128), 256, 0, stream>>>(
        h1, vW2, vb2, v, MT, CC, CC, 0);
    // 3. qpe (argmax-frozen)
    qpe_kernel<<<(BB * NWW * QQ + 255) / 256, 256, 0, stream>>>(qf, qpe);
    // 4-5. query layer 1, both heads (one launch, 600x2 blocks)
    sgemm_dual2<<<dim3((BB * NWW * QQ + 63) / 64, 2), 64, 0, stream>>>(
        qpe, s1W1, s1b1, qh, qpe, s2W1, s2b1, qh2, BB * NWW, QQ, QQ, 1);
    // 6-7. query layer 2, both heads (one launch, 1024x2 blocks)
    sgemm_dual2<<<dim3((BB * NWW * CC + 63) / 64, 2), 64, 0, stream>>>(
        qh, s1W2, s1b2, enc1, qh2, s2W2, s2b2, enc2, BB * NWW, CC, QQ, 0);
    // 8. sim
    sim_kernel<<<BB * (TT / 8), 256, 0, stream>>>(v, enc1, sim);
    // 8b. pu into h1 (dead until step 11)
    pu_kernel<<<(BB * PUL * (CC / 4) + 255) / 256, 256, 0, stream>>>(v, h1);
    // 9. mod (argmax verbatim; modulate via pu)
    mod_kernel<<<BB * LL, 256, 0, stream>>>(h1, sim, enc2, modb);
    // 10. x = mod @ mW + mb   [MX, MD]  (bf16 MFMA)
    gemm_bf16_kernel<<<dim3((MX + 127) / 128, MDD / 128), 256, 0, stream>>>(
        (const short*)modb, (const short*)mWt, mb, x, MX, MDD, CC, 0);
    // 11. hpred = relu(mod @ pW1 + pb1)  [ML, C], K=2048 (bf16 MFMA; h1 reused)
    gemm_bf16_kernel<<<dim3((ML + 127) / 128, CC / 128), 256, 0, stream>>>(
        (const short*)modb, (const short*)pW1t, pb1, h1, ML, CC, NCC * CC, 1);
    // 12. pred head -> out (wave-parallel)
    pred2w_kernel<<<(ML + 3) / 4, 256, 0, stream>>>(h1, pW2, pb2, out);
    // 13. ragged adaptive max-pool, two-stage (sim buffer reused as scratch)
    pool1_kernel<<<BB * SS * NSUB, 256, 0, stream>>>(x, vlen, sim);
    pool2_kernel<<<BB * SS, 256, 0, stream>>>(sim, feat);
    // 14. start/end heads
    stend_kernel<<<128, 64, 0, stream>>>(feat, stW, stb, enW, enb, out);
}

// Round 13
// 397.222 us; speedup vs baseline: 1.1699x; 1.0282x over previous
//
#include <hip/hip_runtime.h>
#include <hip/hip_bf16.h>
#include <math.h>

#define BB 4
#define TT 2048
#define CC 512
#define QQ 300
#define NWW 32
#define MDD 256
#define WSS 16
#define NCC 4
#define SS 16
#define LL (TT - WSS + 1)   // 2033
#define NSUB 8
#define PUL (TT - 3)        // 2045 pu rows per batch

typedef __attribute__((ext_vector_type(8))) short short8;
typedef __attribute__((ext_vector_type(4))) short short4v;
typedef __attribute__((ext_vector_type(4))) float f32x4;

// ---------------------------------------------------------------------------
// PE add — expression kept VERBATIM identical to the frozen path.
// ---------------------------------------------------------------------------
__device__ __forceinline__ void pe_add4(f32x4& v, int t, int gk0)
{
    #pragma unroll
    for (int j = 0; j < 4; j++) {
        int gk = gk0 + j;
        float di = expf((float)(gk & ~1) * (-9.210340371976184f / (float)CC));
        float ang = (float)t * di;
        v[j] += (gk & 1) ? cosf(ang) : sinf(ang);
    }
}

// ---------------------------------------------------------------------------
// fp32 GEMM for the v-path (steps 1,2). BIT-IDENTICAL VALUES: per output a
// single fp32 accumulator, k strictly ascending, one `acc += a*b` statement.
// R8/R12 version: 64x128, BK=32, dbuf, one barrier/K-step, 2 blocks/CU.
// Harness-proven incl. post-timing determinism. (BK=16 variant is BANNED —
// R11 diverged across graph replays.)
// ---------------------------------------------------------------------------
template<int PE>
__global__ __launch_bounds__(256, 2) void gemm_f32_fast(
    const float* __restrict__ A, const float* __restrict__ Bm,
    const float* __restrict__ bias, float* __restrict__ Cm,
    int M, int N, int K, int do_relu)
{
    __shared__ float As[2][32][68];    // k-major, padded
    __shared__ float Bs[2][32][128];
    const int bm = blockIdx.x * 64;
    const int bn = blockIdx.y * 128;
    const int tid = threadIdx.x;
    const int tx = tid & 31;        // n-quad: n0 = tx*4
    const int ty = tid >> 5;        // m-oct: m0 = ty*8

    float acc[8][4] = {};
    f32x4 pa[2], pb[4];
    int am[2], akq[2], bkr[4], bnq[4];
    #pragma unroll
    for (int i = 0; i < 2; i++) {
        int idx = i * 256 + tid;
        am[i] = idx >> 3; akq[i] = (idx & 7) * 4;      // A: 64 rows x 32 k
    }
    #pragma unroll
    for (int i = 0; i < 4; i++) {
        int idx = i * 256 + tid;
        bkr[i] = idx >> 5; bnq[i] = (idx & 31) * 4;    // B: 32 k x 128 n
    }

    const int nk0 = K / 32;
    #pragma unroll
    for (int i = 0; i < 2; i++) {
        pa[i] = *(const f32x4*)(A + (size_t)(bm + am[i]) * K + akq[i]);
        if (PE) pe_add4(pa[i], (bm + am[i]) & (TT - 1), akq[i]);
    }
    #pragma unroll
    for (int i = 0; i < 4; i++)
        pb[i] = *(const f32x4*)(Bm + (size_t)bkr[i] * N + bn + bnq[i]);

    int buf = 0;
    for (int k0i = 0; ; k0i++) {
        #pragma unroll
        for (int i = 0; i < 2; i++)
            #pragma unroll
            for (int j = 0; j < 4; j++) As[buf][akq[i] + j][am[i]] = pa[i][j];
        #pragma unroll
        for (int i = 0; i < 4; i++)
            *(f32x4*)&Bs[buf][bkr[i]][bnq[i]] = pb[i];
        __syncthreads();            // single barrier per K-step (dbuf)
        if (k0i + 1 < nk0) {
            int k0 = (k0i + 1) * 32;
            #pragma unroll
            for (int i = 0; i < 2; i++) {
                pa[i] = *(const f32x4*)(A + (size_t)(bm + am[i]) * K + k0 + akq[i]);
                if (PE) pe_add4(pa[i], (bm + am[i]) & (TT - 1), k0 + akq[i]);
            }
            #pragma unroll
            for (int i = 0; i < 4; i++)
                pb[i] = *(const f32x4*)(Bm + (size_t)(k0 + bkr[i]) * N + bn + bnq[i]);
        }
        #pragma unroll 8
        for (int kk = 0; kk < 32; kk++) {
            f32x4 a0 = *(const f32x4*)&As[buf][kk][ty * 8];
            f32x4 a1 = *(const f32x4*)&As[buf][kk][ty * 8 + 4];
            f32x4 b0 = *(const f32x4*)&Bs[buf][kk][tx * 4];
            #pragma unroll
            for (int i2 = 0; i2 < 4; i2++)
                #pragma unroll
                for (int j2 = 0; j2 < 4; j2++) {
                    acc[i2][j2]     += a0[i2] * b0[j2];
                    acc[i2 + 4][j2] += a1[i2] * b0[j2];
                }
        }
        buf ^= 1;
        if (k0i + 1 == nk0) break;
    }

    #pragma unroll
    for (int i = 0; i < 8; i++) {
        int gm = bm + ty * 8 + i;
        f32x4 o;
        #pragma unroll
        for (int j = 0; j < 4; j++) {
            float v0 = acc[i][j] + bias[bn + tx * 4 + j];
            if (do_relu) v0 = fmaxf(v0, 0.f);
            o[j] = v0;
        }
        *(f32x4*)(Cm + (size_t)gm * N + bn + tx * 4) = o;
    }
}

// ---------------------------------------------------------------------------
// q + PE  (argmax-frozen)
// ---------------------------------------------------------------------------
__global__ void qpe_kernel(const float* __restrict__ q, float* __restrict__ out)
{
    int idx = blockIdx.x * 256 + threadIdx.x;
    if (idx >= BB * NWW * QQ) return;
    int qi = idx % QQ;
    int w  = (idx / QQ) % NWW;
    float di = expf((float)(qi & ~1) * (-9.210340371976184f / (float)QQ));
    float ang = (float)w * di;
    out[idx] = q[idx] + ((qi & 1) ? cosf(ang) : sinf(ang));
}

// ---------------------------------------------------------------------------
// Dual small GEMM with per-head A/W/C (blockIdx.y = head). Per output the
// PROVEN bit-identical strict ascending-k fmaf chain with group-10 prefetch.
// ---------------------------------------------------------------------------
__global__ __launch_bounds__(64) void sgemm_dual2(
    const float* __restrict__ A1, const float* __restrict__ W1,
    const float* __restrict__ b1, float* __restrict__ C1,
    const float* __restrict__ A2, const float* __restrict__ W2,
    const float* __restrict__ b2, float* __restrict__ C2,
    int M, int N, int K, int do_relu)
{
    int id = blockIdx.x * 64 + threadIdx.x;
    if (id >= M * N) return;
    const float* A = blockIdx.y ? A2 : A1;
    const float* B = blockIdx.y ? W2 : W1;
    const float* bias = blockIdx.y ? b2 : b1;
    float* C = blockIdx.y ? C2 : C1;
    int m = id / N, n = id % N;
    const float* a = A + (size_t)m * K;
    const float* b = B + n;
    float acc = 0.f;
    int k = 0;
    for (; k + 10 <= K; k += 10) {
        float av[10], bv[10];
        #pragma unroll
        for (int u = 0; u < 10; u++) av[u] = a[k + u];
        #pragma unroll
        for (int u = 0; u < 10; u++) bv[u] = b[(size_t)(k + u) * N];
        #pragma unroll
        for (int u = 0; u < 10; u++) acc = fmaf(av[u], bv[u], acc);
    }
    for (; k < K; k++) acc = fmaf(a[k], b[(size_t)k * N], acc);
    float val = acc + bias[n];
    if (do_relu) val = fmaxf(val, 0.f);
    C[id] = val;
}

// ---------------------------------------------------------------------------
// bf16 MFMA GEMM, R13: BK=64 (32 MFMA per barrier-pair, half the barriers of
// the R3 version), padded LDS rows (72 shorts -> 2-way bank alias, free).
// PARTIAL=1: split-K over blockIdx.z — each z computes Kp of the full K and
// writes a raw fp32 partial at C + z*M*N (no bias/relu).
// ---------------------------------------------------------------------------
template<int PARTIAL>
__global__ __launch_bounds__(256) void gemm_bf16_k64(
    const short* __restrict__ A, int lda,
    const short* __restrict__ Bt, int ldb,
    const float* __restrict__ bias, float* __restrict__ C,
    int M, int N, int Kp, int do_relu)
{
    __shared__ short As[128][72];
    __shared__ short Bs[128][72];
    const int bm = blockIdx.x * 128;
    const int bn = blockIdx.y * 128;
    const int kbase = PARTIAL ? blockIdx.z * Kp : 0;
    float* Cout = PARTIAL ? C + (size_t)blockIdx.z * ((size_t)M * N) : C;
    const int tid = threadIdx.x;
    const int wave = tid >> 6, lane = tid & 63;
    const int wm = (wave & 1) * 64, wn = (wave >> 1) * 64;
    const int l15 = lane & 15;
    const int lk0 = (lane >> 4) * 8;
    const int srow = tid >> 3;        // 0..31
    const int scol = (tid & 7) * 8;   // 0..56

    f32x4 acc[4][4] = {};

    for (int k0 = kbase; k0 < kbase + Kp; k0 += 64) {
        #pragma unroll
        for (int p = 0; p < 4; p++) {
            int row = p * 32 + srow;
            short8 av = {};
            int gm = bm + row;
            if (gm < M) av = *(const short8*)(A + (size_t)gm * lda + k0 + scol);
            *(short8*)&As[row][scol] = av;
            short8 bv = {};
            int gn = bn + row;
            if (gn < N) bv = *(const short8*)(Bt + (size_t)gn * ldb + k0 + scol);
            *(short8*)&Bs[row][scol] = bv;
        }
        __syncthreads();

        #pragma unroll
        for (int ks = 0; ks < 2; ks++) {
            int lk = lk0 + ks * 32;
            short8 af[4], bf[4];
            #pragma unroll
            for (int mi = 0; mi < 4; mi++)
                af[mi] = *(const short8*)&As[wm + mi * 16 + l15][lk];
            #pragma unroll
            for (int ni = 0; ni < 4; ni++)
                bf[ni] = *(const short8*)&Bs[wn + ni * 16 + l15][lk];
            #pragma unroll
            for (int mi = 0; mi < 4; mi++)
                #pragma unroll
                for (int ni = 0; ni < 4; ni++)
                    acc[mi][ni] = __builtin_amdgcn_mfma_f32_16x16x32_bf16(
                        af[mi], bf[ni], acc[mi][ni], 0, 0, 0);
        }
        __syncthreads();
    }

    // C/D layout: col = lane&15, row = (lane>>4)*4 + reg   [m89-verified]
    #pragma unroll
    for (int mi = 0; mi < 4; mi++) {
        int row0 = bm + wm + mi * 16 + (lane >> 4) * 4;
        #pragma unroll
        for (int ni = 0; ni < 4; ni++) {
            int col = bn + wn + ni * 16 + l15;
            float bsv = (!PARTIAL && bias) ? bias[col] : 0.f;
            #pragma unroll
            for (int r = 0; r < 4; r++) {
                int grow = row0 + r;
                if (grow >= M) continue;
                float val = acc[mi][ni][r] + bsv;
                if (!PARTIAL && do_relu) val = fmaxf(val, 0.f);
                Cout[(size_t)grow * N + col] = val;
            }
        }
    }
}

// ---------------------------------------------------------------------------
// split-K combine: out = relu(p0 + p1 + bias)   (continuous path)
// ---------------------------------------------------------------------------
__global__ __launch_bounds__(256) void combine_kernel(
    const float* __restrict__ p, const float* __restrict__ bias,
    float* __restrict__ outh, int M, int N)
{
    int idx = blockIdx.x * 256 + threadIdx.x;
    if (idx >= M * N) return;
    int n = idx % N;
    float v = p[idx] + p[(size_t)M * N + idx] + bias[n];
    outh[idx] = fmaxf(v, 0.f);
}

// ---------------------------------------------------------------------------
// LDS-tiled transpose+convert: dst[n][k] = bf16(src[k][n]). K,N % 32 == 0.
// ---------------------------------------------------------------------------
__global__ __launch_bounds__(256) void convT2_kernel(
    const float* __restrict__ src, __hip_bfloat16* __restrict__ dst,
    int K, int N)
{
    __shared__ float t[32][33];
    int c = threadIdx.x & 31, r4 = threadIdx.x >> 5;   // 32 x 8
    int n0 = blockIdx.x * 32, k0 = blockIdx.y * 32;
    #pragma unroll
    for (int rr = 0; rr < 32; rr += 8)
        t[rr + r4][c] = src[(size_t)(k0 + rr + r4) * N + n0 + c];
    __syncthreads();
    #pragma unroll
    for (int rr = 0; rr < 32; rr += 8)
        dst[(size_t)(n0 + rr + r4) * K + k0 + c] = __float2bfloat16(t[c][rr + r4]);
}

// ---------------------------------------------------------------------------
// sim[b,t,w] = sum_c v[b,t,c] * enc1[b,w,c]   (bit-identical chain)
// ---------------------------------------------------------------------------
__global__ __launch_bounds__(256) void sim_kernel(
    const float* __restrict__ v, const float* __restrict__ enc1,
    float* __restrict__ sim)
{
    __shared__ float vs[8][CC];
    int blk = blockIdx.x;
    int b  = blk / (TT / 8);
    int t0 = (blk % (TT / 8)) * 8;
    int tid = threadIdx.x;
    for (int i = tid; i < 8 * (CC / 4); i += 256) {
        int r = i / (CC / 4), c = i % (CC / 4);
        *(f32x4*)&vs[r][c * 4] =
            *(const f32x4*)(v + ((size_t)b * TT + t0 + r) * CC + c * 4);
    }
    __syncthreads();
    int w  = tid & 31;
    int tt = tid >> 5;
    const f32x4* e4 = (const f32x4*)(enc1 + ((size_t)b * NWW + w) * CC);
    const f32x4* v4 = (const f32x4*)vs[tt];
    float s = 0.f;
    #pragma unroll 4
    for (int kq = 0; kq < CC / 4; kq++) {
        f32x4 vv = v4[kq], ee = e4[kq];
        s = fmaf(vv[0], ee[0], s);
        s = fmaf(vv[1], ee[1], s);
        s = fmaf(vv[2], ee[2], s);
        s = fmaf(vv[3], ee[3], s);
    }
    sim[((size_t)b * TT + t0 + tt) * NWW + w] = s;
}

// ---------------------------------------------------------------------------
// pu[b,t,:] = 0.25*(((v[t]+v[t+1])+v[t+2])+v[t+3])  — expression verbatim.
// ---------------------------------------------------------------------------
__global__ __launch_bounds__(256) void pu_kernel(
    const float* __restrict__ v, float* __restrict__ pu)
{
    int idx = blockIdx.x * 256 + threadIdx.x;     // over B*PUL*(C/4)
    if (idx >= BB * PUL * (CC / 4)) return;
    int q = idx % (CC / 4);
    int t = (idx / (CC / 4)) % PUL;
    int b = idx / ((CC / 4) * PUL);
    const float* vp = v + ((size_t)b * TT + t) * CC + q * 4;
    f32x4 r0 = *(const f32x4*)vp;
    f32x4 r1 = *(const f32x4*)(vp + CC);
    f32x4 r2 = *(const f32x4*)(vp + 2 * CC);
    f32x4 r3 = *(const f32x4*)(vp + 3 * CC);
    f32x4 o;
    #pragma unroll
    for (int j = 0; j < 4; j++)
        o[j] = 0.25f * (((r0[j] + r1[j]) + r2[j]) + r3[j]);
    *(f32x4*)(pu + ((size_t)b * PUL + t) * CC + q * 4) = o;
}

// ---------------------------------------------------------------------------
// Per (b,l): bel argmax (VERBATIM frozen code) + gather + modulate via pu
// ---------------------------------------------------------------------------
__global__ __launch_bounds__(256) void mod_kernel(
    const float* __restrict__ pu, const float* __restrict__ sim,
    const float* __restrict__ enc2, __hip_bfloat16* __restrict__ modb)
{
    int blk = blockIdx.x;                  // b*L + l
    int b = blk / LL, l = blk % LL;
    int tid = threadIdx.x;
    int cch = tid >> 6;
    int lane = tid & 63;
    int t0 = l + cch * 4;

    int w = lane & 31;
    const float* sp = sim + ((size_t)b * TT + t0) * NWW + w;
    float bel = sp[0] + sp[NWW] + sp[2 * NWW] + sp[3 * NWW];
    int idx = w;
    #pragma unroll
    for (int m = 1; m < 32; m <<= 1) {
        float ov = __shfl_xor(bel, m);
        int   oi = __shfl_xor(idx, m);
        if (ov > bel || (ov == bel && oi < idx)) { bel = ov; idx = oi; }
    }

    const f32x4* e2 = (const f32x4*)(enc2 + ((size_t)b * NWW + idx) * CC);
    const f32x4* pq = (const f32x4*)(pu + ((size_t)b * PUL + t0) * CC);
    __hip_bfloat16* mp = modb + (((size_t)blk) * NCC + cch) * CC;
    #pragma unroll
    for (int q = lane; q < CC / 4; q += 64) {
        f32x4 e = e2[q], p = pq[q];
        short4v o;
        #pragma unroll
        for (int j = 0; j < 4; j++) {
            __hip_bfloat16 h = __float2bfloat16(e[j] * p[j]);
            o[j] = *(short*)&h;
        }
        *(short4v*)(mp + q * 4) = o;
    }
}

// ---------------------------------------------------------------------------
// pred head 2, wave-parallel: one wave per row, both outputs.
// ---------------------------------------------------------------------------
__global__ __launch_bounds__(256) void pred2w_kernel(
    const float* __restrict__ hpred, const float* __restrict__ pW2,
    const float* __restrict__ pb2, float* __restrict__ out)
{
    int row = blockIdx.x * 4 + (threadIdx.x >> 6);
    if (row >= BB * LL) return;
    int lane = threadIdx.x & 63;
    const float* h = hpred + (size_t)row * CC + lane * 8;
    f32x4 h0 = *(const f32x4*)h;
    f32x4 h1 = *(const f32x4*)(h + 4);
    const float* wp = pW2 + lane * 16;
    f32x4 w0 = *(const f32x4*)wp;
    f32x4 w1 = *(const f32x4*)(wp + 4);
    f32x4 w2 = *(const f32x4*)(wp + 8);
    f32x4 w3 = *(const f32x4*)(wp + 12);
    float s0 = h0[0]*w0[0] + h0[1]*w0[2] + h0[2]*w1[0] + h0[3]*w1[2]
             + h1[0]*w2[0] + h1[1]*w2[2] + h1[2]*w3[0] + h1[3]*w3[2];
    float s1 = h0[0]*w0[1] + h0[1]*w0[3] + h0[2]*w1[1] + h0[3]*w1[3]
             + h1[0]*w2[1] + h1[1]*w2[3] + h1[2]*w3[1] + h1[3]*w3[3];
    #pragma unroll
    for (int m = 32; m; m >>= 1) {
        s0 += __shfl_xor(s0, m);
        s1 += __shfl_xor(s1, m);
    }
    if (lane == 0) {
        int b = row / LL, l = row % LL;
        out[((size_t)b * 2 + 0) * LL + l] = s0 + pb2[0];
        out[((size_t)b * 2 + 1) * LL + l] = s1 + pb2[1];
    }
}

// ---------------------------------------------------------------------------
// ragged adaptive max-pool, two-stage (max is exactly associative)
// ---------------------------------------------------------------------------
__global__ __launch_bounds__(256) void pool1_kernel(
    const float* __restrict__ x, const int* __restrict__ vis_len,
    float* __restrict__ scratch)
{
    int blk = blockIdx.x;             // ((b*SS + s)*NSUB + sub)
    int sub = blk % NSUB;
    int s   = (blk / NSUB) % SS;
    int b   = blk / (NSUB * SS);
    int n = vis_len[b] * NCC;
    int st = (n * s) / SS;
    int en = (n * (s + 1) + SS - 1) / SS;
    int len = en - st;
    int j0 = st + (len * sub) / NSUB;
    int j1 = st + (len * (sub + 1)) / NSUB;
    int md = threadIdx.x;
    float m = -INFINITY;
    const float* xp = x + (size_t)b * (LL * NCC) * MDD + md;
    for (int j = j0; j < j1; j++) m = fmaxf(m, xp[(size_t)j * MDD]);
    scratch[(size_t)blk * MDD + md] = m;
}

__global__ __launch_bounds__(256) void pool2_kernel(
    const float* __restrict__ scratch, float* __restrict__ feat)
{
    int blk = blockIdx.x;  // b*SS + s
    int md = threadIdx.x;
    const float* sp = scratch + (size_t)blk * NSUB * MDD + md;
    float m = sp[0];
    #pragma unroll
    for (int i = 1; i < NSUB; i++) m = fmaxf(m, sp[(size_t)i * MDD]);
    int b = blk / SS, s = blk % SS;
    feat[(size_t)b * MDD * SS + md * SS + s] = m;
}

// ---------------------------------------------------------------------------
// start/end heads
// ---------------------------------------------------------------------------
__global__ void stend_kernel(const float* __restrict__ feat,
                             const float* __restrict__ stW, const float* __restrict__ stb,
                             const float* __restrict__ enW, const float* __restrict__ enb,
                             float* __restrict__ out)
{
    int bid = blockIdx.x;                  // 0..127
    int which = bid >> 6;
    int r = bid & 63;
    int b = r >> 4, s = r & 15;
    int lane = threadIdx.x;                // 64
    const float* W  = which ? enW : stW;
    const float* bb = which ? enb : stb;
    const float* f  = feat + (size_t)b * MDD * SS;
    float acc = 0.f;
    for (int k = lane; k < MDD * SS; k += 64) acc += f[k] * W[(size_t)k * SS + s];
    #pragma unroll
    for (int m = 32; m; m >>= 1) acc += __shfl_xor(acc, m);
    if (lane == 0)
        out[(size_t)BB * 2 * LL + which * (BB * SS) + b * SS + s] = acc + bb[s];
}

// ---------------------------------------------------------------------------
extern "C" void kernel_launch(void* const* d_in, const int* in_sizes, int n_in,
                              void* d_out, int out_size, void* d_ws, size_t ws_size,
                              hipStream_t stream)
{
    const float* vis  = (const float*)d_in[0];
    const float* qf   = (const float*)d_in[1];
    const float* vW1  = (const float*)d_in[2];  const float* vb1 = (const float*)d_in[3];
    const float* vW2  = (const float*)d_in[4];  const float* vb2 = (const float*)d_in[5];
    const float* s1W1 = (const float*)d_in[6];  const float* s1b1= (const float*)d_in[7];
    const float* s1W2 = (const float*)d_in[8];  const float* s1b2= (const float*)d_in[9];
    const float* s2W1 = (const float*)d_in[10]; const float* s2b1= (const float*)d_in[11];
    const float* s2W2 = (const float*)d_in[12]; const float* s2b2= (const float*)d_in[13];
    const float* pW1  = (const float*)d_in[14]; const float* pb1 = (const float*)d_in[15];
    const float* pW2  = (const float*)d_in[16]; const float* pb2 = (const float*)d_in[17];
    const float* mW   = (const float*)d_in[18]; const float* mb  = (const float*)d_in[19];
    const float* stW  = (const float*)d_in[20]; const float* stb = (const float*)d_in[21];
    const float* enW  = (const float*)d_in[22]; const float* enb = (const float*)d_in[23];
    const int*   vlen = (const int*)d_in[24];
    float* out = (float*)d_out;

    // workspace layout (floats; 16B-aligned blocks)
    float* ws   = (float*)d_ws;
    float* h1   = ws;                                 // B*T*C (reused: pu, then hpred)
    float* v    = h1   + (size_t)BB * TT * CC;        // B*T*C
    float* qpe  = v    + (size_t)BB * TT * CC;        // B*NW*Q
    float* qh   = qpe  + (size_t)BB * NWW * QQ;       // B*NW*Q  (qh1)
    float* enc1 = qh   + (size_t)BB * NWW * QQ;       // B*NW*C
    float* enc2 = enc1 + (size_t)BB * NWW * CC;       // B*NW*C
    float* sim  = enc2 + (size_t)BB * NWW * CC;       // B*T*NW (reused as pool scratch)
    float* feat = sim  + (size_t)BB * TT * NWW;       // B*MD*S
    float* x    = feat + (size_t)BB * MDD * SS;       // B*L*NC*MD (also split-K scratch)
    float* fend = x    + (size_t)BB * LL * NCC * MDD;
    __hip_bfloat16* modb = (__hip_bfloat16*)fend;                  // MX*C bf16
    __hip_bfloat16* pW1t = modb + (size_t)BB * LL * NCC * CC;      // 512*2048 bf16
    __hip_bfloat16* mWt  = pW1t + (size_t)CC * (NCC * CC);         // 256*512 bf16
    float* qh2 = (float*)(mWt + (size_t)CC * MDD);                 // B*NW*Q (qh2)

    const int MT = BB * TT;            // 8192
    const int ML = BB * LL;            // 8132
    const int MX = BB * LL * NCC;      // 32528

    // weight convert+transpose (bf16), LDS-tiled
    convT2_kernel<<<dim3(CC / 32, (NCC * CC) / 32), 256, 0, stream>>>(pW1, pW1t, NCC * CC, CC);
    convT2_kernel<<<dim3(MDD / 32, CC / 32), 256, 0, stream>>>(mW, mWt, CC, MDD);

    // 1. h1 = relu(PE(vis) @ vW1 + vb1)   (fp32 — bit-identical values)
    gemm_f32_fast<1><<<dim3(MT / 64, CC / 128), 256, 0, stream>>>(
        vis, vW1, vb1, h1, MT, CC, CC, 1);
    // 2. v = h1 @ vW2 + vb2
    gemm_f32_fast<0><<<dim3(MT / 64, CC / 128), 256, 0, stream>>>(
        h1, vW2, vb2, v, MT, CC, CC, 0);
    // 3. qpe (argmax-frozen)
    qpe_kernel<<<(BB * NWW * QQ + 255) / 256, 256, 0, stream>>>(qf, qpe);
    // 4-5. query layer 1, both heads
    sgemm_dual2<<<dim3((BB * NWW * QQ + 63) / 64, 2), 64, 0, stream>>>(
        qpe, s1W1, s1b1, qh, qpe, s2W1, s2b1, qh2, BB * NWW, QQ, QQ, 1);
    // 6-7. query layer 2, both heads
    sgemm_dual2<<<dim3((BB * NWW * CC + 63) / 64, 2), 64, 0, stream>>>(
        qh, s1W2, s1b2, enc1, qh2, s2W2, s2b2, enc2, BB * NWW, CC, QQ, 0);
    // 8. sim
    sim_kernel<<<BB * (TT / 8), 256, 0, stream>>>(v, enc1, sim);
    // 8b. pu into h1 (dead until step 11's combine)
    pu_kernel<<<(BB * PUL * (CC / 4) + 255) / 256, 256, 0, stream>>>(v, h1);
    // 9. mod (argmax verbatim; modulate via pu)
    mod_kernel<<<BB * LL, 256, 0, stream>>>(h1, sim, enc2, modb);
    // 11. hpred = relu(mod @ pW1 + pb1)  [ML, C], K=2048 — split-K=2 (bf16
    //     MFMA): partials in the (dead until step 10) x region, combine -> h1
    gemm_bf16_k64<1><<<dim3(ML / 128 + 1, CC / 128, 2), 256, 0, stream>>>(
        (const short*)modb, NCC * CC, (const short*)pW1t, NCC * CC,
        nullptr, x, ML, CC, (NCC * CC) / 2, 0);
    combine_kernel<<<((size_t)ML * CC + 255) / 256, 256, 0, stream>>>(
        x, pb1, h1, ML, CC);
    // 10. x = mod @ mW + mb   [MX, MD]  (bf16 MFMA, overwrites partials)
    gemm_bf16_k64<0><<<dim3((MX + 127) / 128, MDD / 128), 256, 0, stream>>>(
        (const short*)modb, CC, (const short*)mWt, CC, mb, x, MX, MDD, CC, 0);
    // 12. pred head -> out (wave-parallel)
    pred2w_kernel<<<(ML + 3) / 4, 256, 0, stream>>>(h1, pW2, pb2, out);
    // 13. ragged adaptive max-pool, two-stage (sim buffer reused as scratch)
    pool1_kernel<<<BB * SS * NSUB, 256, 0, stream>>>(x, vlen, sim);
    pool2_kernel<<<BB * SS, 256, 0, stream>>>(sim, feat);
    // 14. start/end heads
    stend_kernel<<<128, 64, 0, stream>>>(feat, stW, stb, enW, enb, out);
}

// Round 14
// 360.928 us; speedup vs baseline: 1.2876x; 1.1006x over previous
//
#include <hip/hip_runtime.h>
#include <hip/hip_bf16.h>
#include <math.h>

#define BB 4
#define TT 2048
#define CC 512
#define QQ 300
#define NWW 32
#define MDD 256
#define WSS 16
#define NCC 4
#define SS 16
#define LL (TT - WSS + 1)   // 2033
#define NSUB 8
#define PUL (TT - 3)        // 2045 pu rows per batch

typedef __attribute__((ext_vector_type(8))) short short8;
typedef __attribute__((ext_vector_type(4))) short short4v;
typedef __attribute__((ext_vector_type(4))) float f32x4;

// ---------------------------------------------------------------------------
// PE add — expression kept VERBATIM identical to the frozen path.
// ---------------------------------------------------------------------------
__device__ __forceinline__ void pe_add4(f32x4& v, int t, int gk0)
{
    #pragma unroll
    for (int j = 0; j < 4; j++) {
        int gk = gk0 + j;
        float di = expf((float)(gk & ~1) * (-9.210340371976184f / (float)CC));
        float ang = (float)t * di;
        v[j] += (gk & 1) ? cosf(ang) : sinf(ang);
    }
}

// ---------------------------------------------------------------------------
// fp32 GEMM for the v-path (steps 1,2). BIT-IDENTICAL VALUES: per output a
// single fp32 accumulator, k strictly ascending, one `acc += a*b` statement.
// R8/R12 version — harness-proven incl. post-timing determinism (4 runs).
// LDS-instruction-bound at ~55% VALUBusy; structural limit under the
// frozen-chain constraint. (BK=16 variant BANNED — R11 replay divergence.)
// ---------------------------------------------------------------------------
template<int PE>
__global__ __launch_bounds__(256, 2) void gemm_f32_fast(
    const float* __restrict__ A, const float* __restrict__ Bm,
    const float* __restrict__ bias, float* __restrict__ Cm,
    int M, int N, int K, int do_relu)
{
    __shared__ float As[2][32][68];    // k-major, padded
    __shared__ float Bs[2][32][128];
    const int bm = blockIdx.x * 64;
    const int bn = blockIdx.y * 128;
    const int tid = threadIdx.x;
    const int tx = tid & 31;        // n-quad: n0 = tx*4
    const int ty = tid >> 5;        // m-oct: m0 = ty*8

    float acc[8][4] = {};
    f32x4 pa[2], pb[4];
    int am[2], akq[2], bkr[4], bnq[4];
    #pragma unroll
    for (int i = 0; i < 2; i++) {
        int idx = i * 256 + tid;
        am[i] = idx >> 3; akq[i] = (idx & 7) * 4;      // A: 64 rows x 32 k
    }
    #pragma unroll
    for (int i = 0; i < 4; i++) {
        int idx = i * 256 + tid;
        bkr[i] = idx >> 5; bnq[i] = (idx & 31) * 4;    // B: 32 k x 128 n
    }

    const int nk0 = K / 32;
    #pragma unroll
    for (int i = 0; i < 2; i++) {
        pa[i] = *(const f32x4*)(A + (size_t)(bm + am[i]) * K + akq[i]);
        if (PE) pe_add4(pa[i], (bm + am[i]) & (TT - 1), akq[i]);
    }
    #pragma unroll
    for (int i = 0; i < 4; i++)
        pb[i] = *(const f32x4*)(Bm + (size_t)bkr[i] * N + bn + bnq[i]);

    int buf = 0;
    for (int k0i = 0; ; k0i++) {
        #pragma unroll
        for (int i = 0; i < 2; i++)
            #pragma unroll
            for (int j = 0; j < 4; j++) As[buf][akq[i] + j][am[i]] = pa[i][j];
        #pragma unroll
        for (int i = 0; i < 4; i++)
            *(f32x4*)&Bs[buf][bkr[i]][bnq[i]] = pb[i];
        __syncthreads();            // single barrier per K-step (dbuf)
        if (k0i + 1 < nk0) {
            int k0 = (k0i + 1) * 32;
            #pragma unroll
            for (int i = 0; i < 2; i++) {
                pa[i] = *(const f32x4*)(A + (size_t)(bm + am[i]) * K + k0 + akq[i]);
                if (PE) pe_add4(pa[i], (bm + am[i]) & (TT - 1), k0 + akq[i]);
            }
            #pragma unroll
            for (int i = 0; i < 4; i++)
                pb[i] = *(const f32x4*)(Bm + (size_t)(k0 + bkr[i]) * N + bn + bnq[i]);
        }
        #pragma unroll 8
        for (int kk = 0; kk < 32; kk++) {
            f32x4 a0 = *(const f32x4*)&As[buf][kk][ty * 8];
            f32x4 a1 = *(const f32x4*)&As[buf][kk][ty * 8 + 4];
            f32x4 b0 = *(const f32x4*)&Bs[buf][kk][tx * 4];
            #pragma unroll
            for (int i2 = 0; i2 < 4; i2++)
                #pragma unroll
                for (int j2 = 0; j2 < 4; j2++) {
                    acc[i2][j2]     += a0[i2] * b0[j2];
                    acc[i2 + 4][j2] += a1[i2] * b0[j2];
                }
        }
        buf ^= 1;
        if (k0i + 1 == nk0) break;
    }

    #pragma unroll
    for (int i = 0; i < 8; i++) {
        int gm = bm + ty * 8 + i;
        f32x4 o;
        #pragma unroll
        for (int j = 0; j < 4; j++) {
            float v0 = acc[i][j] + bias[bn + tx * 4 + j];
            if (do_relu) v0 = fmaxf(v0, 0.f);
            o[j] = v0;
        }
        *(f32x4*)(Cm + (size_t)gm * N + bn + tx * 4) = o;
    }
}

// ---------------------------------------------------------------------------
// q + PE  (argmax-frozen)
// ---------------------------------------------------------------------------
__global__ void qpe_kernel(const float* __restrict__ q, float* __restrict__ out)
{
    int idx = blockIdx.x * 256 + threadIdx.x;
    if (idx >= BB * NWW * QQ) return;
    int qi = idx % QQ;
    int w  = (idx / QQ) % NWW;
    float di = expf((float)(qi & ~1) * (-9.210340371976184f / (float)QQ));
    float ang = (float)w * di;
    out[idx] = q[idx] + ((qi & 1) ? cosf(ang) : sinf(ang));
}

// ---------------------------------------------------------------------------
// Dual small GEMM with per-head A/W/C (blockIdx.y = head). Per output the
// PROVEN bit-identical strict ascending-k fmaf chain with group-10 prefetch.
// ---------------------------------------------------------------------------
__global__ __launch_bounds__(64) void sgemm_dual2(
    const float* __restrict__ A1, const float* __restrict__ W1,
    const float* __restrict__ b1, float* __restrict__ C1,
    const float* __restrict__ A2, const float* __restrict__ W2,
    const float* __restrict__ b2, float* __restrict__ C2,
    int M, int N, int K, int do_relu)
{
    int id = blockIdx.x * 64 + threadIdx.x;
    if (id >= M * N) return;
    const float* A = blockIdx.y ? A2 : A1;
    const float* B = blockIdx.y ? W2 : W1;
    const float* bias = blockIdx.y ? b2 : b1;
    float* C = blockIdx.y ? C2 : C1;
    int m = id / N, n = id % N;
    const float* a = A + (size_t)m * K;
    const float* b = B + n;
    float acc = 0.f;
    int k = 0;
    for (; k + 10 <= K; k += 10) {
        float av[10], bv[10];
        #pragma unroll
        for (int u = 0; u < 10; u++) av[u] = a[k + u];
        #pragma unroll
        for (int u = 0; u < 10; u++) bv[u] = b[(size_t)(k + u) * N];
        #pragma unroll
        for (int u = 0; u < 10; u++) acc = fmaf(av[u], bv[u], acc);
    }
    for (; k < K; k++) acc = fmaf(a[k], b[(size_t)k * N], acc);
    float val = acc + bias[n];
    if (do_relu) val = fmaxf(val, 0.f);
    C[id] = val;
}

// ---------------------------------------------------------------------------
// bf16 MFMA GEMM, BK=64, padded LDS rows. PARTIAL=1: split-K over blockIdx.z,
// raw fp32 partial at C + z*M*N (no bias/relu).
// ---------------------------------------------------------------------------
template<int PARTIAL>
__global__ __launch_bounds__(256) void gemm_bf16_k64(
    const short* __restrict__ A, int lda,
    const short* __restrict__ Bt, int ldb,
    const float* __restrict__ bias, float* __restrict__ C,
    int M, int N, int Kp, int do_relu)
{
    __shared__ short As[128][72];
    __shared__ short Bs[128][72];
    const int bm = blockIdx.x * 128;
    const int bn = blockIdx.y * 128;
    const int kbase = PARTIAL ? blockIdx.z * Kp : 0;
    float* Cout = PARTIAL ? C + (size_t)blockIdx.z * ((size_t)M * N) : C;
    const int tid = threadIdx.x;
    const int wave = tid >> 6, lane = tid & 63;
    const int wm = (wave & 1) * 64, wn = (wave >> 1) * 64;
    const int l15 = lane & 15;
    const int lk0 = (lane >> 4) * 8;
    const int srow = tid >> 3;        // 0..31
    const int scol = (tid & 7) * 8;   // 0..56

    f32x4 acc[4][4] = {};

    for (int k0 = kbase; k0 < kbase + Kp; k0 += 64) {
        #pragma unroll
        for (int p = 0; p < 4; p++) {
            int row = p * 32 + srow;
            short8 av = {};
            int gm = bm + row;
            if (gm < M) av = *(const short8*)(A + (size_t)gm * lda + k0 + scol);
            *(short8*)&As[row][scol] = av;
            short8 bv = {};
            int gn = bn + row;
            if (gn < N) bv = *(const short8*)(Bt + (size_t)gn * ldb + k0 + scol);
            *(short8*)&Bs[row][scol] = bv;
        }
        __syncthreads();

        #pragma unroll
        for (int ks = 0; ks < 2; ks++) {
            int lk = lk0 + ks * 32;
            short8 af[4], bf[4];
            #pragma unroll
            for (int mi = 0; mi < 4; mi++)
                af[mi] = *(const short8*)&As[wm + mi * 16 + l15][lk];
            #pragma unroll
            for (int ni = 0; ni < 4; ni++)
                bf[ni] = *(const short8*)&Bs[wn + ni * 16 + l15][lk];
            #pragma unroll
            for (int mi = 0; mi < 4; mi++)
                #pragma unroll
                for (int ni = 0; ni < 4; ni++)
                    acc[mi][ni] = __builtin_amdgcn_mfma_f32_16x16x32_bf16(
                        af[mi], bf[ni], acc[mi][ni], 0, 0, 0);
        }
        __syncthreads();
    }

    #pragma unroll
    for (int mi = 0; mi < 4; mi++) {
        int row0 = bm + wm + mi * 16 + (lane >> 4) * 4;
        #pragma unroll
        for (int ni = 0; ni < 4; ni++) {
            int col = bn + wn + ni * 16 + l15;
            float bsv = (!PARTIAL && bias) ? bias[col] : 0.f;
            #pragma unroll
            for (int r = 0; r < 4; r++) {
                int grow = row0 + r;
                if (grow >= M) continue;
                float val = acc[mi][ni][r] + bsv;
                if (!PARTIAL && do_relu) val = fmaxf(val, 0.f);
                Cout[(size_t)grow * N + col] = val;
            }
        }
    }
}

// ---------------------------------------------------------------------------
// LDS-tiled transpose+convert: dst[n][k] = bf16(src[k][n]). K,N % 32 == 0.
// ---------------------------------------------------------------------------
__global__ __launch_bounds__(256) void convT2_kernel(
    const float* __restrict__ src, __hip_bfloat16* __restrict__ dst,
    int K, int N)
{
    __shared__ float t[32][33];
    int c = threadIdx.x & 31, r4 = threadIdx.x >> 5;   // 32 x 8
    int n0 = blockIdx.x * 32, k0 = blockIdx.y * 32;
    #pragma unroll
    for (int rr = 0; rr < 32; rr += 8)
        t[rr + r4][c] = src[(size_t)(k0 + rr + r4) * N + n0 + c];
    __syncthreads();
    #pragma unroll
    for (int rr = 0; rr < 32; rr += 8)
        dst[(size_t)(n0 + rr + r4) * K + k0 + c] = __float2bfloat16(t[c][rr + r4]);
}

// ---------------------------------------------------------------------------
// sim[b,t,w] = sum_c v[b,t,c] * enc1[b,w,c].
// R14: 16 t-rows/block, 2 rows per thread (e4 regs reused across both dots).
// Per-output chain UNCHANGED: independent accumulator, k strictly ascending,
// fmaf order identical -> bit-identical (argmax-safe).
// ---------------------------------------------------------------------------
__global__ __launch_bounds__(256) void sim_kernel(
    const float* __restrict__ v, const float* __restrict__ enc1,
    float* __restrict__ sim)
{
    __shared__ float vs[16][CC];
    int blk = blockIdx.x;
    int b  = blk / (TT / 16);
    int t0 = (blk % (TT / 16)) * 16;
    int tid = threadIdx.x;
    for (int i = tid; i < 16 * (CC / 4); i += 256) {
        int r = i / (CC / 4), c = i % (CC / 4);
        *(f32x4*)&vs[r][c * 4] =
            *(const f32x4*)(v + ((size_t)b * TT + t0 + r) * CC + c * 4);
    }
    __syncthreads();
    int w  = tid & 31;
    int tt = (tid >> 5) * 2;       // 0,2,..,14
    const f32x4* e4 = (const f32x4*)(enc1 + ((size_t)b * NWW + w) * CC);
    const f32x4* va = (const f32x4*)vs[tt];
    const f32x4* vb = (const f32x4*)vs[tt + 1];
    float s0 = 0.f, s1 = 0.f;
    #pragma unroll 4
    for (int kq = 0; kq < CC / 4; kq++) {
        f32x4 ee = e4[kq];
        f32x4 aa = va[kq], bb = vb[kq];
        s0 = fmaf(aa[0], ee[0], s0);
        s0 = fmaf(aa[1], ee[1], s0);
        s0 = fmaf(aa[2], ee[2], s0);
        s0 = fmaf(aa[3], ee[3], s0);
        s1 = fmaf(bb[0], ee[0], s1);
        s1 = fmaf(bb[1], ee[1], s1);
        s1 = fmaf(bb[2], ee[2], s1);
        s1 = fmaf(bb[3], ee[3], s1);
    }
    sim[((size_t)b * TT + t0 + tt) * NWW + w] = s0;
    sim[((size_t)b * TT + t0 + tt + 1) * NWW + w] = s1;
}

// ---------------------------------------------------------------------------
// pu[b,t,:] = 0.25*(((v[t]+v[t+1])+v[t+2])+v[t+3])  — expression verbatim.
// ---------------------------------------------------------------------------
__global__ __launch_bounds__(256) void pu_kernel(
    const float* __restrict__ v, float* __restrict__ pu)
{
    int idx = blockIdx.x * 256 + threadIdx.x;     // over B*PUL*(C/4)
    if (idx >= BB * PUL * (CC / 4)) return;
    int q = idx % (CC / 4);
    int t = (idx / (CC / 4)) % PUL;
    int b = idx / ((CC / 4) * PUL);
    const float* vp = v + ((size_t)b * TT + t) * CC + q * 4;
    f32x4 r0 = *(const f32x4*)vp;
    f32x4 r1 = *(const f32x4*)(vp + CC);
    f32x4 r2 = *(const f32x4*)(vp + 2 * CC);
    f32x4 r3 = *(const f32x4*)(vp + 3 * CC);
    f32x4 o;
    #pragma unroll
    for (int j = 0; j < 4; j++)
        o[j] = 0.25f * (((r0[j] + r1[j]) + r2[j]) + r3[j]);
    *(f32x4*)(pu + ((size_t)b * PUL + t) * CC + q * 4) = o;
}

// ---------------------------------------------------------------------------
// Per (b,l): bel argmax (VERBATIM frozen code) + gather + modulate via pu
// ---------------------------------------------------------------------------
__global__ __launch_bounds__(256) void mod_kernel(
    const float* __restrict__ pu, const float* __restrict__ sim,
    const float* __restrict__ enc2, __hip_bfloat16* __restrict__ modb)
{
    int blk = blockIdx.x;                  // b*L + l
    int b = blk / LL, l = blk % LL;
    int tid = threadIdx.x;
    int cch = tid >> 6;
    int lane = tid & 63;
    int t0 = l + cch * 4;

    int w = lane & 31;
    const float* sp = sim + ((size_t)b * TT + t0) * NWW + w;
    float bel = sp[0] + sp[NWW] + sp[2 * NWW] + sp[3 * NWW];
    int idx = w;
    #pragma unroll
    for (int m = 1; m < 32; m <<= 1) {
        float ov = __shfl_xor(bel, m);
        int   oi = __shfl_xor(idx, m);
        if (ov > bel || (ov == bel && oi < idx)) { bel = ov; idx = oi; }
    }

    const f32x4* e2 = (const f32x4*)(enc2 + ((size_t)b * NWW + idx) * CC);
    const f32x4* pq = (const f32x4*)(pu + ((size_t)b * PUL + t0) * CC);
    __hip_bfloat16* mp = modb + (((size_t)blk) * NCC + cch) * CC;
    #pragma unroll
    for (int q = lane; q < CC / 4; q += 64) {
        f32x4 e = e2[q], p = pq[q];
        short4v o;
        #pragma unroll
        for (int j = 0; j < 4; j++) {
            __hip_bfloat16 h = __float2bfloat16(e[j] * p[j]);
            o[j] = *(short*)&h;
        }
        *(short4v*)(mp + q * 4) = o;
    }
}

// ---------------------------------------------------------------------------
// pred head 2 FUSED with split-K combine: h = relu(p0 + p1 + pb1) computed
// inline (identical expression order to the old combine kernel -> identical
// values), then the wave dot. Removes the combine launch + h1 roundtrip.
// ---------------------------------------------------------------------------
__global__ __launch_bounds__(256) void pred2w_fused(
    const float* __restrict__ p,      // partials: p0 at 0, p1 at ML*CC
    const float* __restrict__ pb1,
    const float* __restrict__ pW2, const float* __restrict__ pb2,
    float* __restrict__ out)
{
    const int ML = BB * LL;
    int row = blockIdx.x * 4 + (threadIdx.x >> 6);
    if (row >= ML) return;
    int lane = threadIdx.x & 63;
    size_t off = (size_t)row * CC + lane * 8;
    f32x4 a0 = *(const f32x4*)(p + off);
    f32x4 a1 = *(const f32x4*)(p + off + 4);
    f32x4 c0 = *(const f32x4*)(p + (size_t)ML * CC + off);
    f32x4 c1 = *(const f32x4*)(p + (size_t)ML * CC + off + 4);
    f32x4 bb0 = *(const f32x4*)(pb1 + lane * 8);
    f32x4 bb1 = *(const f32x4*)(pb1 + lane * 8 + 4);
    f32x4 h0, h1;
    #pragma unroll
    for (int j = 0; j < 4; j++) {
        h0[j] = fmaxf(a0[j] + c0[j] + bb0[j], 0.f);
        h1[j] = fmaxf(a1[j] + c1[j] + bb1[j], 0.f);
    }
    const float* wp = pW2 + lane * 16;
    f32x4 w0 = *(const f32x4*)wp;
    f32x4 w1 = *(const f32x4*)(wp + 4);
    f32x4 w2 = *(const f32x4*)(wp + 8);
    f32x4 w3 = *(const f32x4*)(wp + 12);
    float s0 = h0[0]*w0[0] + h0[1]*w0[2] + h0[2]*w1[0] + h0[3]*w1[2]
             + h1[0]*w2[0] + h1[1]*w2[2] + h1[2]*w3[0] + h1[3]*w3[2];
    float s1 = h0[0]*w0[1] + h0[1]*w0[3] + h0[2]*w1[1] + h0[3]*w1[3]
             + h1[0]*w2[1] + h1[1]*w2[3] + h1[2]*w3[1] + h1[3]*w3[3];
    #pragma unroll
    for (int m = 32; m; m >>= 1) {
        s0 += __shfl_xor(s0, m);
        s1 += __shfl_xor(s1, m);
    }
    if (lane == 0) {
        int b = row / LL, l = row % LL;
        out[((size_t)b * 2 + 0) * LL + l] = s0 + pb2[0];
        out[((size_t)b * 2 + 1) * LL + l] = s1 + pb2[1];
    }
}

// ---------------------------------------------------------------------------
// ragged adaptive max-pool, two-stage (max is exactly associative)
// ---------------------------------------------------------------------------
__global__ __launch_bounds__(256) void pool1_kernel(
    const float* __restrict__ x, const int* __restrict__ vis_len,
    float* __restrict__ scratch)
{
    int blk = blockIdx.x;             // ((b*SS + s)*NSUB + sub)
    int sub = blk % NSUB;
    int s   = (blk / NSUB) % SS;
    int b   = blk / (NSUB * SS);
    int n = vis_len[b] * NCC;
    int st = (n * s) / SS;
    int en = (n * (s + 1) + SS - 1) / SS;
    int len = en - st;
    int j0 = st + (len * sub) / NSUB;
    int j1 = st + (len * (sub + 1)) / NSUB;
    int md = threadIdx.x;
    float m = -INFINITY;
    const float* xp = x + (size_t)b * (LL * NCC) * MDD + md;
    for (int j = j0; j < j1; j++) m = fmaxf(m, xp[(size_t)j * MDD]);
    scratch[(size_t)blk * MDD + md] = m;
}

__global__ __launch_bounds__(256) void pool2_kernel(
    const float* __restrict__ scratch, float* __restrict__ feat)
{
    int blk = blockIdx.x;  // b*SS + s
    int md = threadIdx.x;
    const float* sp = scratch + (size_t)blk * NSUB * MDD + md;
    float m = sp[0];
    #pragma unroll
    for (int i = 1; i < NSUB; i++) m = fmaxf(m, sp[(size_t)i * MDD]);
    int b = blk / SS, s = blk % SS;
    feat[(size_t)b * MDD * SS + md * SS + s] = m;
}

// ---------------------------------------------------------------------------
// start/end heads
// ---------------------------------------------------------------------------
__global__ void stend_kernel(const float* __restrict__ feat,
                             const float* __restrict__ stW, const float* __restrict__ stb,
                             const float* __restrict__ enW, const float* __restrict__ enb,
                             float* __restrict__ out)
{
    int bid = blockIdx.x;                  // 0..127
    int which = bid >> 6;
    int r = bid & 63;
    int b = r >> 4, s = r & 15;
    int lane = threadIdx.x;                // 64
    const float* W  = which ? enW : stW;
    const float* bb = which ? enb : stb;
    const float* f  = feat + (size_t)b * MDD * SS;
    float acc = 0.f;
    for (int k = lane; k < MDD * SS; k += 64) acc += f[k] * W[(size_t)k * SS + s];
    #pragma unroll
    for (int m = 32; m; m >>= 1) acc += __shfl_xor(acc, m);
    if (lane == 0)
        out[(size_t)BB * 2 * LL + which * (BB * SS) + b * SS + s] = acc + bb[s];
}

// ---------------------------------------------------------------------------
extern "C" void kernel_launch(void* const* d_in, const int* in_sizes, int n_in,
                              void* d_out, int out_size, void* d_ws, size_t ws_size,
                              hipStream_t stream)
{
    const float* vis  = (const float*)d_in[0];
    const float* qf   = (const float*)d_in[1];
    const float* vW1  = (const float*)d_in[2];  const float* vb1 = (const float*)d_in[3];
    const float* vW2  = (const float*)d_in[4];  const float* vb2 = (const float*)d_in[5];
    const float* s1W1 = (const float*)d_in[6];  const float* s1b1= (const float*)d_in[7];
    const float* s1W2 = (const float*)d_in[8];  const float* s1b2= (const float*)d_in[9];
    const float* s2W1 = (const float*)d_in[10]; const float* s2b1= (const float*)d_in[11];
    const float* s2W2 = (const float*)d_in[12]; const float* s2b2= (const float*)d_in[13];
    const float* pW1  = (const float*)d_in[14]; const float* pb1 = (const float*)d_in[15];
    const float* pW2  = (const float*)d_in[16]; const float* pb2 = (const float*)d_in[17];
    const float* mW   = (const float*)d_in[18]; const float* mb  = (const float*)d_in[19];
    const float* stW  = (const float*)d_in[20]; const float* stb = (const float*)d_in[21];
    const float* enW  = (const float*)d_in[22]; const float* enb = (const float*)d_in[23];
    const int*   vlen = (const int*)d_in[24];
    float* out = (float*)d_out;

    // workspace layout (floats; 16B-aligned blocks)
    float* ws   = (float*)d_ws;
    float* h1   = ws;                                 // B*T*C (reused as pu)
    float* v    = h1   + (size_t)BB * TT * CC;        // B*T*C
    float* qpe  = v    + (size_t)BB * TT * CC;        // B*NW*Q
    float* qh   = qpe  + (size_t)BB * NWW * QQ;       // B*NW*Q  (qh1)
    float* enc1 = qh   + (size_t)BB * NWW * QQ;       // B*NW*C
    float* enc2 = enc1 + (size_t)BB * NWW * CC;       // B*NW*C
    float* sim  = enc2 + (size_t)BB * NWW * CC;       // B*T*NW (reused as pool scratch)
    float* feat = sim  + (size_t)BB * TT * NWW;       // B*MD*S
    float* x    = feat + (size_t)BB * MDD * SS;       // B*L*NC*MD (also split-K scratch)
    float* fend = x    + (size_t)BB * LL * NCC * MDD;
    __hip_bfloat16* modb = (__hip_bfloat16*)fend;                  // MX*C bf16
    __hip_bfloat16* pW1t = modb + (size_t)BB * LL * NCC * CC;      // 512*2048 bf16
    __hip_bfloat16* mWt  = pW1t + (size_t)CC * (NCC * CC);         // 256*512 bf16
    float* qh2 = (float*)(mWt + (size_t)CC * MDD);                 // B*NW*Q (qh2)

    const int MT = BB * TT;            // 8192
    const int ML = BB * LL;            // 8132
    const int MX = BB * LL * NCC;      // 32528

    // weight convert+transpose (bf16), LDS-tiled
    convT2_kernel<<<dim3(CC / 32, (NCC * CC) / 32), 256, 0, stream>>>(pW1, pW1t, NCC * CC, CC);
    convT2_kernel<<<dim3(MDD / 32, CC / 32), 256, 0, stream>>>(mW, mWt, CC, MDD);

    // 1. h1 = relu(PE(vis) @ vW1 + vb1)   (fp32 — bit-identical values)
    gemm_f32_fast<1><<<dim3(MT / 64, CC / 128), 256, 0, stream>>>(
        vis, vW1, vb1, h1, MT, CC, CC, 1);
    // 2. v = h1 @ vW2 + vb2
    gemm_f32_fast<0><<<dim3(MT / 64, CC / 128), 256, 0, stream>>>(
        h1, vW2, vb2, v, MT, CC, CC, 0);
    // 3. qpe (argmax-frozen)
    qpe_kernel<<<(BB * NWW * QQ + 255) / 256, 256, 0, stream>>>(qf, qpe);
    // 4-5. query layer 1, both heads
    sgemm_dual2<<<dim3((BB * NWW * QQ + 63) / 64, 2), 64, 0, stream>>>(
        qpe, s1W1, s1b1, qh, qpe, s2W1, s2b1, qh2, BB * NWW, QQ, QQ, 1);
    // 6-7. query layer 2, both heads
    sgemm_dual2<<<dim3((BB * NWW * CC + 63) / 64, 2), 64, 0, stream>>>(
        qh, s1W2, s1b2, enc1, qh2, s2W2, s2b2, enc2, BB * NWW, CC, QQ, 0);
    // 8. sim (2 rows/thread, chain-preserving)
    sim_kernel<<<BB * (TT / 16), 256, 0, stream>>>(v, enc1, sim);
    // 8b. pu into h1
    pu_kernel<<<(BB * PUL * (CC / 4) + 255) / 256, 256, 0, stream>>>(v, h1);
    // 9. mod (argmax verbatim; modulate via pu)
    mod_kernel<<<BB * LL, 256, 0, stream>>>(h1, sim, enc2, modb);
    // 11. hpred partials: split-K=2 bf16 MFMA into the (dead) x region
    gemm_bf16_k64<1><<<dim3(ML / 128 + 1, CC / 128, 2), 256, 0, stream>>>(
        (const short*)modb, NCC * CC, (const short*)pW1t, NCC * CC,
        nullptr, x, ML, CC, (NCC * CC) / 2, 0);
    // 12. pred head (combine fused) -> out; reads x partials
    pred2w_fused<<<(ML + 3) / 4, 256, 0, stream>>>(x, pb1, pW2, pb2, out);
    // 10. x = mod @ mW + mb   [MX, MD]  (bf16 MFMA, overwrites partials)
    gemm_bf16_k64<0><<<dim3((MX + 127) / 128, MDD / 128), 256, 0, stream>>>(
        (const short*)modb, CC, (const short*)mWt, CC, mb, x, MX, MDD, CC, 0);
    // 13. ragged adaptive max-pool, two-stage (sim buffer reused as scratch)
    pool1_kernel<<<BB * SS * NSUB, 256, 0, stream>>>(x, vlen, sim);
    pool2_kernel<<<BB * SS, 256, 0, stream>>>(sim, feat);
    // 14. start/end heads
    stend_kernel<<<128, 64, 0, stream>>>(feat, stW, stb, enW, enb, out);
}

// Round 15
// 359.272 us; speedup vs baseline: 1.2935x; 1.0046x over previous
//
#include <hip/hip_runtime.h>
#include <hip/hip_bf16.h>
#include <math.h>

#define BB 4
#define TT 2048
#define CC 512
#define QQ 300
#define NWW 32
#define MDD 256
#define WSS 16
#define NCC 4
#define SS 16
#define LL (TT - WSS + 1)   // 2033
#define NSUB 8
#define PUL (TT - 3)        // 2045 pu rows per batch

typedef __attribute__((ext_vector_type(8))) short short8;
typedef __attribute__((ext_vector_type(4))) short short4v;
typedef __attribute__((ext_vector_type(4))) float f32x4;

// ---------------------------------------------------------------------------
// PE add — expression kept VERBATIM identical to the frozen path.
// ---------------------------------------------------------------------------
__device__ __forceinline__ void pe_add4(f32x4& v, int t, int gk0)
{
    #pragma unroll
    for (int j = 0; j < 4; j++) {
        int gk = gk0 + j;
        float di = expf((float)(gk & ~1) * (-9.210340371976184f / (float)CC));
        float ang = (float)t * di;
        v[j] += (gk & 1) ? cosf(ang) : sinf(ang);
    }
}

// ---------------------------------------------------------------------------
// fp32 GEMM for the v-path (steps 1,2). BIT-IDENTICAL VALUES: per output a
// single fp32 accumulator, k strictly ascending, one `acc += a*b` statement.
// R8/R12 version — harness-proven incl. post-timing determinism (5 runs).
// LDS-instruction-bound at ~55% VALUBusy; structural limit under the
// frozen-chain constraint. (BK=16 variant BANNED — R11 replay divergence.)
// ---------------------------------------------------------------------------
template<int PE>
__global__ __launch_bounds__(256, 2) void gemm_f32_fast(
    const float* __restrict__ A, const float* __restrict__ Bm,
    const float* __restrict__ bias, float* __restrict__ Cm,
    int M, int N, int K, int do_relu)
{
    __shared__ float As[2][32][68];    // k-major, padded
    __shared__ float Bs[2][32][128];
    const int bm = blockIdx.x * 64;
    const int bn = blockIdx.y * 128;
    const int tid = threadIdx.x;
    const int tx = tid & 31;        // n-quad: n0 = tx*4
    const int ty = tid >> 5;        // m-oct: m0 = ty*8

    float acc[8][4] = {};
    f32x4 pa[2], pb[4];
    int am[2], akq[2], bkr[4], bnq[4];
    #pragma unroll
    for (int i = 0; i < 2; i++) {
        int idx = i * 256 + tid;
        am[i] = idx >> 3; akq[i] = (idx & 7) * 4;      // A: 64 rows x 32 k
    }
    #pragma unroll
    for (int i = 0; i < 4; i++) {
        int idx = i * 256 + tid;
        bkr[i] = idx >> 5; bnq[i] = (idx & 31) * 4;    // B: 32 k x 128 n
    }

    const int nk0 = K / 32;
    #pragma unroll
    for (int i = 0; i < 2; i++) {
        pa[i] = *(const f32x4*)(A + (size_t)(bm + am[i]) * K + akq[i]);
        if (PE) pe_add4(pa[i], (bm + am[i]) & (TT - 1), akq[i]);
    }
    #pragma unroll
    for (int i = 0; i < 4; i++)
        pb[i] = *(const f32x4*)(Bm + (size_t)bkr[i] * N + bn + bnq[i]);

    int buf = 0;
    for (int k0i = 0; ; k0i++) {
        #pragma unroll
        for (int i = 0; i < 2; i++)
            #pragma unroll
            for (int j = 0; j < 4; j++) As[buf][akq[i] + j][am[i]] = pa[i][j];
        #pragma unroll
        for (int i = 0; i < 4; i++)
            *(f32x4*)&Bs[buf][bkr[i]][bnq[i]] = pb[i];
        __syncthreads();            // single barrier per K-step (dbuf)
        if (k0i + 1 < nk0) {
            int k0 = (k0i + 1) * 32;
            #pragma unroll
            for (int i = 0; i < 2; i++) {
                pa[i] = *(const f32x4*)(A + (size_t)(bm + am[i]) * K + k0 + akq[i]);
                if (PE) pe_add4(pa[i], (bm + am[i]) & (TT - 1), k0 + akq[i]);
            }
            #pragma unroll
            for (int i = 0; i < 4; i++)
                pb[i] = *(const f32x4*)(Bm + (size_t)(k0 + bkr[i]) * N + bn + bnq[i]);
        }
        #pragma unroll 8
        for (int kk = 0; kk < 32; kk++) {
            f32x4 a0 = *(const f32x4*)&As[buf][kk][ty * 8];
            f32x4 a1 = *(const f32x4*)&As[buf][kk][ty * 8 + 4];
            f32x4 b0 = *(const f32x4*)&Bs[buf][kk][tx * 4];
            #pragma unroll
            for (int i2 = 0; i2 < 4; i2++)
                #pragma unroll
                for (int j2 = 0; j2 < 4; j2++) {
                    acc[i2][j2]     += a0[i2] * b0[j2];
                    acc[i2 + 4][j2] += a1[i2] * b0[j2];
                }
        }
        buf ^= 1;
        if (k0i + 1 == nk0) break;
    }

    #pragma unroll
    for (int i = 0; i < 8; i++) {
        int gm = bm + ty * 8 + i;
        f32x4 o;
        #pragma unroll
        for (int j = 0; j < 4; j++) {
            float v0 = acc[i][j] + bias[bn + tx * 4 + j];
            if (do_relu) v0 = fmaxf(v0, 0.f);
            o[j] = v0;
        }
        *(f32x4*)(Cm + (size_t)gm * N + bn + tx * 4) = o;
    }
}

// ---------------------------------------------------------------------------
// q + PE  (argmax-frozen)
// ---------------------------------------------------------------------------
__global__ void qpe_kernel(const float* __restrict__ q, float* __restrict__ out)
{
    int idx = blockIdx.x * 256 + threadIdx.x;
    if (idx >= BB * NWW * QQ) return;
    int qi = idx % QQ;
    int w  = (idx / QQ) % NWW;
    float di = expf((float)(qi & ~1) * (-9.210340371976184f / (float)QQ));
    float ang = (float)w * di;
    out[idx] = q[idx] + ((qi & 1) ? cosf(ang) : sinf(ang));
}

// ---------------------------------------------------------------------------
// Dual small GEMM with per-head A/W/C (blockIdx.y = head). Per output the
// PROVEN bit-identical strict ascending-k fmaf chain with group-10 prefetch.
// ---------------------------------------------------------------------------
__global__ __launch_bounds__(64) void sgemm_dual2(
    const float* __restrict__ A1, const float* __restrict__ W1,
    const float* __restrict__ b1, float* __restrict__ C1,
    const float* __restrict__ A2, const float* __restrict__ W2,
    const float* __restrict__ b2, float* __restrict__ C2,
    int M, int N, int K, int do_relu)
{
    int id = blockIdx.x * 64 + threadIdx.x;
    if (id >= M * N) return;
    const float* A = blockIdx.y ? A2 : A1;
    const float* B = blockIdx.y ? W2 : W1;
    const float* bias = blockIdx.y ? b2 : b1;
    float* C = blockIdx.y ? C2 : C1;
    int m = id / N, n = id % N;
    const float* a = A + (size_t)m * K;
    const float* b = B + n;
    float acc = 0.f;
    int k = 0;
    for (; k + 10 <= K; k += 10) {
        float av[10], bv[10];
        #pragma unroll
        for (int u = 0; u < 10; u++) av[u] = a[k + u];
        #pragma unroll
        for (int u = 0; u < 10; u++) bv[u] = b[(size_t)(k + u) * N];
        #pragma unroll
        for (int u = 0; u < 10; u++) acc = fmaf(av[u], bv[u], acc);
    }
    for (; k < K; k++) acc = fmaf(a[k], b[(size_t)k * N], acc);
    float val = acc + bias[n];
    if (do_relu) val = fmaxf(val, 0.f);
    C[id] = val;
}

// ---------------------------------------------------------------------------
// bf16 MFMA GEMM, BK=64, padded LDS rows.
// PARTIAL=1: split-K over blockIdx.z, raw fp32 partial at C + z*M*N.
// OUT16=1: write bf16 output to C16 (continuous path only).
// SKIP=1: early-exit blocks whose rows are all invalid (>= vlen*NC within
// their batch) — those rows are never read by the pool. vlen-uniform branch,
// deterministic per call.
// ---------------------------------------------------------------------------
template<int PARTIAL, int OUT16, int SKIP>
__global__ __launch_bounds__(256) void gemm_bf16_k64(
    const short* __restrict__ A, int lda,
    const short* __restrict__ Bt, int ldb,
    const float* __restrict__ bias, float* __restrict__ C,
    __hip_bfloat16* __restrict__ C16, const int* __restrict__ vlen,
    int M, int N, int Kp, int do_relu)
{
    __shared__ short As[128][72];
    __shared__ short Bs[128][72];
    const int bm = blockIdx.x * 128;
    const int bn = blockIdx.y * 128;

    if (SKIP) {
        // rows [bm, bm+128): valid iff some row has rowInBatch < vlen[b]*NC
        int b0 = bm / (LL * NCC);
        int rib = bm - b0 * (LL * NCC);
        int last = bm + 127 < M - 1 ? bm + 127 : M - 1;
        int b1 = last / (LL * NCC);
        bool valid = (rib < vlen[b0] * NCC) || (b1 != b0);
        if (!valid) return;
    }

    const int kbase = PARTIAL ? blockIdx.z * Kp : 0;
    float* Cout = PARTIAL ? C + (size_t)blockIdx.z * ((size_t)M * N) : C;
    const int tid = threadIdx.x;
    const int wave = tid >> 6, lane = tid & 63;
    const int wm = (wave & 1) * 64, wn = (wave >> 1) * 64;
    const int l15 = lane & 15;
    const int lk0 = (lane >> 4) * 8;
    const int srow = tid >> 3;        // 0..31
    const int scol = (tid & 7) * 8;   // 0..56

    f32x4 acc[4][4] = {};

    for (int k0 = kbase; k0 < kbase + Kp; k0 += 64) {
        #pragma unroll
        for (int p = 0; p < 4; p++) {
            int row = p * 32 + srow;
            short8 av = {};
            int gm = bm + row;
            if (gm < M) av = *(const short8*)(A + (size_t)gm * lda + k0 + scol);
            *(short8*)&As[row][scol] = av;
            short8 bv = {};
            int gn = bn + row;
            if (gn < N) bv = *(const short8*)(Bt + (size_t)gn * ldb + k0 + scol);
            *(short8*)&Bs[row][scol] = bv;
        }
        __syncthreads();

        #pragma unroll
        for (int ks = 0; ks < 2; ks++) {
            int lk = lk0 + ks * 32;
            short8 af[4], bf[4];
            #pragma unroll
            for (int mi = 0; mi < 4; mi++)
                af[mi] = *(const short8*)&As[wm + mi * 16 + l15][lk];
            #pragma unroll
            for (int ni = 0; ni < 4; ni++)
                bf[ni] = *(const short8*)&Bs[wn + ni * 16 + l15][lk];
            #pragma unroll
            for (int mi = 0; mi < 4; mi++)
                #pragma unroll
                for (int ni = 0; ni < 4; ni++)
                    acc[mi][ni] = __builtin_amdgcn_mfma_f32_16x16x32_bf16(
                        af[mi], bf[ni], acc[mi][ni], 0, 0, 0);
        }
        __syncthreads();
    }

    #pragma unroll
    for (int mi = 0; mi < 4; mi++) {
        int row0 = bm + wm + mi * 16 + (lane >> 4) * 4;
        #pragma unroll
        for (int ni = 0; ni < 4; ni++) {
            int col = bn + wn + ni * 16 + l15;
            float bsv = (!PARTIAL && bias) ? bias[col] : 0.f;
            #pragma unroll
            for (int r = 0; r < 4; r++) {
                int grow = row0 + r;
                if (grow >= M) continue;
                float val = acc[mi][ni][r] + bsv;
                if (!PARTIAL && do_relu) val = fmaxf(val, 0.f);
                if (OUT16)
                    C16[(size_t)grow * N + col] = __float2bfloat16(val);
                else
                    Cout[(size_t)grow * N + col] = val;
            }
        }
    }
}

// ---------------------------------------------------------------------------
// Both weight transposes (pW1->pW1t, mW->mWt) in ONE launch, flattened grid.
// Blocks 0..1023: pW1 (K=2048,N=512, 16x64 tiles); 1024..1151: mW (K=512,
// N=256, 8x16 tiles).
// ---------------------------------------------------------------------------
__global__ __launch_bounds__(256) void convT2_dual(
    const float* __restrict__ pW1, __hip_bfloat16* __restrict__ pW1t,
    const float* __restrict__ mW, __hip_bfloat16* __restrict__ mWt)
{
    __shared__ float t[32][33];
    int c = threadIdx.x & 31, r4 = threadIdx.x >> 5;   // 32 x 8
    const float* src; __hip_bfloat16* dst;
    int K, N, n0, k0;
    int id = blockIdx.x;
    if (id < 1024) {
        src = pW1; dst = pW1t; K = NCC * CC; N = CC;
        n0 = (id & 15) * 32; k0 = (id >> 4) * 32;
    } else {
        id -= 1024;
        src = mW; dst = mWt; K = CC; N = MDD;
        n0 = (id & 7) * 32; k0 = (id >> 3) * 32;
    }
    #pragma unroll
    for (int rr = 0; rr < 32; rr += 8)
        t[rr + r4][c] = src[(size_t)(k0 + rr + r4) * N + n0 + c];
    __syncthreads();
    #pragma unroll
    for (int rr = 0; rr < 32; rr += 8)
        dst[(size_t)(n0 + rr + r4) * K + k0 + c] = __float2bfloat16(t[c][rr + r4]);
}

// ---------------------------------------------------------------------------
// sim[b,t,w] = sum_c v[b,t,c] * enc1[b,w,c].  16 rows/block, 2 rows/thread.
// Per-output chain UNCHANGED (argmax-safe).
// ---------------------------------------------------------------------------
__global__ __launch_bounds__(256) void sim_kernel(
    const float* __restrict__ v, const float* __restrict__ enc1,
    float* __restrict__ sim)
{
    __shared__ float vs[16][CC];
    int blk = blockIdx.x;
    int b  = blk / (TT / 16);
    int t0 = (blk % (TT / 16)) * 16;
    int tid = threadIdx.x;
    for (int i = tid; i < 16 * (CC / 4); i += 256) {
        int r = i / (CC / 4), c = i % (CC / 4);
        *(f32x4*)&vs[r][c * 4] =
            *(const f32x4*)(v + ((size_t)b * TT + t0 + r) * CC + c * 4);
    }
    __syncthreads();
    int w  = tid & 31;
    int tt = (tid >> 5) * 2;       // 0,2,..,14
    const f32x4* e4 = (const f32x4*)(enc1 + ((size_t)b * NWW + w) * CC);
    const f32x4* va = (const f32x4*)vs[tt];
    const f32x4* vb = (const f32x4*)vs[tt + 1];
    float s0 = 0.f, s1 = 0.f;
    #pragma unroll 4
    for (int kq = 0; kq < CC / 4; kq++) {
        f32x4 ee = e4[kq];
        f32x4 aa = va[kq], bb = vb[kq];
        s0 = fmaf(aa[0], ee[0], s0);
        s0 = fmaf(aa[1], ee[1], s0);
        s0 = fmaf(aa[2], ee[2], s0);
        s0 = fmaf(aa[3], ee[3], s0);
        s1 = fmaf(bb[0], ee[0], s1);
        s1 = fmaf(bb[1], ee[1], s1);
        s1 = fmaf(bb[2], ee[2], s1);
        s1 = fmaf(bb[3], ee[3], s1);
    }
    sim[((size_t)b * TT + t0 + tt) * NWW + w] = s0;
    sim[((size_t)b * TT + t0 + tt + 1) * NWW + w] = s1;
}

// ---------------------------------------------------------------------------
// pu[b,t,:] = 0.25*(((v[t]+v[t+1])+v[t+2])+v[t+3])  — expression verbatim.
// ---------------------------------------------------------------------------
__global__ __launch_bounds__(256) void pu_kernel(
    const float* __restrict__ v, float* __restrict__ pu)
{
    int idx = blockIdx.x * 256 + threadIdx.x;     // over B*PUL*(C/4)
    if (idx >= BB * PUL * (CC / 4)) return;
    int q = idx % (CC / 4);
    int t = (idx / (CC / 4)) % PUL;
    int b = idx / ((CC / 4) * PUL);
    const float* vp = v + ((size_t)b * TT + t) * CC + q * 4;
    f32x4 r0 = *(const f32x4*)vp;
    f32x4 r1 = *(const f32x4*)(vp + CC);
    f32x4 r2 = *(const f32x4*)(vp + 2 * CC);
    f32x4 r3 = *(const f32x4*)(vp + 3 * CC);
    f32x4 o;
    #pragma unroll
    for (int j = 0; j < 4; j++)
        o[j] = 0.25f * (((r0[j] + r1[j]) + r2[j]) + r3[j]);
    *(f32x4*)(pu + ((size_t)b * PUL + t) * CC + q * 4) = o;
}

// ---------------------------------------------------------------------------
// Per (b,l): bel argmax (VERBATIM frozen code) + gather + modulate via pu
// ---------------------------------------------------------------------------
__global__ __launch_bounds__(256) void mod_kernel(
    const float* __restrict__ pu, const float* __restrict__ sim,
    const float* __restrict__ enc2, __hip_bfloat16* __restrict__ modb)
{
    int blk = blockIdx.x;                  // b*L + l
    int b = blk / LL, l = blk % LL;
    int tid = threadIdx.x;
    int cch = tid >> 6;
    int lane = tid & 63;
    int t0 = l + cch * 4;

    int w = lane & 31;
    const float* sp = sim + ((size_t)b * TT + t0) * NWW + w;
    float bel = sp[0] + sp[NWW] + sp[2 * NWW] + sp[3 * NWW];
    int idx = w;
    #pragma unroll
    for (int m = 1; m < 32; m <<= 1) {
        float ov = __shfl_xor(bel, m);
        int   oi = __shfl_xor(idx, m);
        if (ov > bel || (ov == bel && oi < idx)) { bel = ov; idx = oi; }
    }

    const f32x4* e2 = (const f32x4*)(enc2 + ((size_t)b * NWW + idx) * CC);
    const f32x4* pq = (const f32x4*)(pu + ((size_t)b * PUL + t0) * CC);
    __hip_bfloat16* mp = modb + (((size_t)blk) * NCC + cch) * CC;
    #pragma unroll
    for (int q = lane; q < CC / 4; q += 64) {
        f32x4 e = e2[q], p = pq[q];
        short4v o;
        #pragma unroll
        for (int j = 0; j < 4; j++) {
            __hip_bfloat16 h = __float2bfloat16(e[j] * p[j]);
            o[j] = *(short*)&h;
        }
        *(short4v*)(mp + q * 4) = o;
    }
}

// ---------------------------------------------------------------------------
// pred head 2 FUSED with split-K combine (values identical to R13/R14).
// ---------------------------------------------------------------------------
__global__ __launch_bounds__(256) void pred2w_fused(
    const float* __restrict__ p,      // partials: p0 at 0, p1 at ML*CC
    const float* __restrict__ pb1,
    const float* __restrict__ pW2, const float* __restrict__ pb2,
    float* __restrict__ out)
{
    const int ML = BB * LL;
    int row = blockIdx.x * 4 + (threadIdx.x >> 6);
    if (row >= ML) return;
    int lane = threadIdx.x & 63;
    size_t off = (size_t)row * CC + lane * 8;
    f32x4 a0 = *(const f32x4*)(p + off);
    f32x4 a1 = *(const f32x4*)(p + off + 4);
    f32x4 c0 = *(const f32x4*)(p + (size_t)ML * CC + off);
    f32x4 c1 = *(const f32x4*)(p + (size_t)ML * CC + off + 4);
    f32x4 bb0 = *(const f32x4*)(pb1 + lane * 8);
    f32x4 bb1 = *(const f32x4*)(pb1 + lane * 8 + 4);
    f32x4 h0, h1;
    #pragma unroll
    for (int j = 0; j < 4; j++) {
        h0[j] = fmaxf(a0[j] + c0[j] + bb0[j], 0.f);
        h1[j] = fmaxf(a1[j] + c1[j] + bb1[j], 0.f);
    }
    const float* wp = pW2 + lane * 16;
    f32x4 w0 = *(const f32x4*)wp;
    f32x4 w1 = *(const f32x4*)(wp + 4);
    f32x4 w2 = *(const f32x4*)(wp + 8);
    f32x4 w3 = *(const f32x4*)(wp + 12);
    float s0 = h0[0]*w0[0] + h0[1]*w0[2] + h0[2]*w1[0] + h0[3]*w1[2]
             + h1[0]*w2[0] + h1[1]*w2[2] + h1[2]*w3[0] + h1[3]*w3[2];
    float s1 = h0[0]*w0[1] + h0[1]*w0[3] + h0[2]*w1[1] + h0[3]*w1[3]
             + h1[0]*w2[1] + h1[1]*w2[3] + h1[2]*w3[1] + h1[3]*w3[3];
    #pragma unroll
    for (int m = 32; m; m >>= 1) {
        s0 += __shfl_xor(s0, m);
        s1 += __shfl_xor(s1, m);
    }
    if (lane == 0) {
        int b = row / LL, l = row % LL;
        out[((size_t)b * 2 + 0) * LL + l] = s0 + pb2[0];
        out[((size_t)b * 2 + 1) * LL + l] = s1 + pb2[1];
    }
}

// ---------------------------------------------------------------------------
// ragged adaptive max-pool, two-stage; x is now bf16.
// ---------------------------------------------------------------------------
__global__ __launch_bounds__(256) void pool1_kernel(
    const __hip_bfloat16* __restrict__ x, const int* __restrict__ vis_len,
    float* __restrict__ scratch)
{
    int blk = blockIdx.x;             // ((b*SS + s)*NSUB + sub)
    int sub = blk % NSUB;
    int s   = (blk / NSUB) % SS;
    int b   = blk / (NSUB * SS);
    int n = vis_len[b] * NCC;
    int st = (n * s) / SS;
    int en = (n * (s + 1) + SS - 1) / SS;
    int len = en - st;
    int j0 = st + (len * sub) / NSUB;
    int j1 = st + (len * (sub + 1)) / NSUB;
    int md = threadIdx.x;
    float m = -INFINITY;
    const __hip_bfloat16* xp = x + (size_t)b * (LL * NCC) * MDD + md;
    for (int j = j0; j < j1; j++)
        m = fmaxf(m, __bfloat162float(xp[(size_t)j * MDD]));
    scratch[(size_t)blk * MDD + md] = m;
}

__global__ __launch_bounds__(256) void pool2_kernel(
    const float* __restrict__ scratch, float* __restrict__ feat)
{
    int blk = blockIdx.x;  // b*SS + s
    int md = threadIdx.x;
    const float* sp = scratch + (size_t)blk * NSUB * MDD + md;
    float m = sp[0];
    #pragma unroll
    for (int i = 1; i < NSUB; i++) m = fmaxf(m, sp[(size_t)i * MDD]);
    int b = blk / SS, s = blk % SS;
    feat[(size_t)b * MDD * SS + md * SS + s] = m;
}

// ---------------------------------------------------------------------------
// start/end heads
// ---------------------------------------------------------------------------
__global__ void stend_kernel(const float* __restrict__ feat,
                             const float* __restrict__ stW, const float* __restrict__ stb,
                             const float* __restrict__ enW, const float* __restrict__ enb,
                             float* __restrict__ out)
{
    int bid = blockIdx.x;                  // 0..127
    int which = bid >> 6;
    int r = bid & 63;
    int b = r >> 4, s = r & 15;
    int lane = threadIdx.x;                // 64
    const float* W  = which ? enW : stW;
    const float* bb = which ? enb : stb;
    const float* f  = feat + (size_t)b * MDD * SS;
    float acc = 0.f;
    for (int k = lane; k < MDD * SS; k += 64) acc += f[k] * W[(size_t)k * SS + s];
    #pragma unroll
    for (int m = 32; m; m >>= 1) acc += __shfl_xor(acc, m);
    if (lane == 0)
        out[(size_t)BB * 2 * LL + which * (BB * SS) + b * SS + s] = acc + bb[s];
}

// ---------------------------------------------------------------------------
extern "C" void kernel_launch(void* const* d_in, const int* in_sizes, int n_in,
                              void* d_out, int out_size, void* d_ws, size_t ws_size,
                              hipStream_t stream)
{
    const float* vis  = (const float*)d_in[0];
    const float* qf   = (const float*)d_in[1];
    const float* vW1  = (const float*)d_in[2];  const float* vb1 = (const float*)d_in[3];
    const float* vW2  = (const float*)d_in[4];  const float* vb2 = (const float*)d_in[5];
    const float* s1W1 = (const float*)d_in[6];  const float* s1b1= (const float*)d_in[7];
    const float* s1W2 = (const float*)d_in[8];  const float* s1b2= (const float*)d_in[9];
    const float* s2W1 = (const float*)d_in[10]; const float* s2b1= (const float*)d_in[11];
    const float* s2W2 = (const float*)d_in[12]; const float* s2b2= (const float*)d_in[13];
    const float* pW1  = (const float*)d_in[14]; const float* pb1 = (const float*)d_in[15];
    const float* pW2  = (const float*)d_in[16]; const float* pb2 = (const float*)d_in[17];
    const float* mW   = (const float*)d_in[18]; const float* mb  = (const float*)d_in[19];
    const float* stW  = (const float*)d_in[20]; const float* stb = (const float*)d_in[21];
    const float* enW  = (const float*)d_in[22]; const float* enb = (const float*)d_in[23];
    const int*   vlen = (const int*)d_in[24];
    float* out = (float*)d_out;

    // workspace layout (floats; 16B-aligned blocks)
    float* ws   = (float*)d_ws;
    float* h1   = ws;                                 // B*T*C (reused as pu)
    float* v    = h1   + (size_t)BB * TT * CC;        // B*T*C
    float* qpe  = v    + (size_t)BB * TT * CC;        // B*NW*Q
    float* qh   = qpe  + (size_t)BB * NWW * QQ;       // B*NW*Q  (qh1)
    float* enc1 = qh   + (size_t)BB * NWW * QQ;       // B*NW*C
    float* enc2 = enc1 + (size_t)BB * NWW * CC;       // B*NW*C
    float* sim  = enc2 + (size_t)BB * NWW * CC;       // B*T*NW (reused as pool scratch)
    float* feat = sim  + (size_t)BB * TT * NWW;       // B*MD*S
    float* x    = feat + (size_t)BB * MDD * SS;       // MX*MD fp32 (split-K scratch;
                                                      // later reused as bf16 x)
    float* fend = x    + (size_t)BB * LL * NCC * MDD;
    __hip_bfloat16* modb = (__hip_bfloat16*)fend;                  // MX*C bf16
    __hip_bfloat16* pW1t = modb + (size_t)BB * LL * NCC * CC;      // 512*2048 bf16
    __hip_bfloat16* mWt  = pW1t + (size_t)CC * (NCC * CC);         // 256*512 bf16
    float* qh2 = (float*)(mWt + (size_t)CC * MDD);                 // B*NW*Q (qh2)
    __hip_bfloat16* xb16 = (__hip_bfloat16*)x;                     // bf16 x view

    const int MT = BB * TT;            // 8192
    const int ML = BB * LL;            // 8132
    const int MX = BB * LL * NCC;      // 32528

    // weight convert+transpose (bf16), ONE launch
    convT2_dual<<<1152, 256, 0, stream>>>(pW1, pW1t, mW, mWt);

    // 1. h1 = relu(PE(vis) @ vW1 + vb1)   (fp32 — bit-identical values)
    gemm_f32_fast<1><<<dim3(MT / 64, CC / 128), 256, 0, stream>>>(
        vis, vW1, vb1, h1, MT, CC, CC, 1);
    // 2. v = h1 @ vW2 + vb2
    gemm_f32_fast<0><<<dim3(MT / 64, CC / 128), 256, 0, stream>>>(
        h1, vW2, vb2, v, MT, CC, CC, 0);
    // 3. qpe (argmax-frozen)
    qpe_kernel<<<(BB * NWW * QQ + 255) / 256, 256, 0, stream>>>(qf, qpe);
    // 4-5. query layer 1, both heads
    sgemm_dual2<<<dim3((BB * NWW * QQ + 63) / 64, 2), 64, 0, stream>>>(
        qpe, s1W1, s1b1, qh, qpe, s2W1, s2b1, qh2, BB * NWW, QQ, QQ, 1);
    // 6-7. query layer 2, both heads
    sgemm_dual2<<<dim3((BB * NWW * CC + 63) / 64, 2), 64, 0, stream>>>(
        qh, s1W2, s1b2, enc1, qh2, s2W2, s2b2, enc2, BB * NWW, CC, QQ, 0);
    // 8. sim (2 rows/thread, chain-preserving)
    sim_kernel<<<BB * (TT / 16), 256, 0, stream>>>(v, enc1, sim);
    // 8b. pu into h1
    pu_kernel<<<(BB * PUL * (CC / 4) + 255) / 256, 256, 0, stream>>>(v, h1);
    // 9. mod (argmax verbatim; modulate via pu)
    mod_kernel<<<BB * LL, 256, 0, stream>>>(h1, sim, enc2, modb);
    // 11. hpred partials: split-K=2 bf16 MFMA into x region (fp32)
    gemm_bf16_k64<1, 0, 0><<<dim3(ML / 128 + 1, CC / 128, 2), 256, 0, stream>>>(
        (const short*)modb, NCC * CC, (const short*)pW1t, NCC * CC,
        nullptr, x, nullptr, nullptr, ML, CC, (NCC * CC) / 2, 0);
    // 12. pred head (combine fused) -> out; reads x partials
    pred2w_fused<<<(ML + 3) / 4, 256, 0, stream>>>(x, pb1, pW2, pb2, out);
    // 10. x = mod @ mW + mb  [MX, MD] -> bf16; skip invalid-row blocks
    gemm_bf16_k64<0, 1, 1><<<dim3((MX + 127) / 128, MDD / 128), 256, 0, stream>>>(
        (const short*)modb, CC, (const short*)mWt, CC, mb, nullptr, xb16, vlen,
        MX, MDD, CC, 0);
    // 13. ragged adaptive max-pool (bf16 x), two-stage
    pool1_kernel<<<BB * SS * NSUB, 256, 0, stream>>>(xb16, vlen, sim);
    pool2_kernel<<<BB * SS, 256, 0, stream>>>(sim, feat);
    // 14. start/end heads
    stend_kernel<<<128, 64, 0, stream>>>(feat, stW, stb, enW, enb, out);
}